// Round 4
// baseline (2208.277 us; speedup 1.0000x reference)
//
#include <hip/hip_runtime.h>
#include <hip/hip_bf16.h>

// ---------------- constants ----------------
constexpr int NN = 40000;   // nodes
constexpr int NE = 400000;  // edges (before self-loops)
constexpr int NSLAB = 20000;

__device__ __forceinline__ unsigned short f2bf(float f) {
    unsigned int u = __float_as_uint(f);
    unsigned int r = (u + 0x7FFFu + ((u >> 16) & 1u)) >> 16;
    return (unsigned short)r;
}

// ---------------- BN ----------------
__global__ void bn_partial(const float* __restrict__ x, int N, int C,
                           float* __restrict__ partial) {
    int ch = threadIdx.x;            // blockDim = 128, C <= 128
    if (ch >= C) return;
    float s = 0.f, sq = 0.f;
    for (int n = blockIdx.x; n < N; n += gridDim.x) {
        float v = x[(size_t)n * C + ch];
        s += v; sq += v * v;
    }
    partial[(size_t)blockIdx.x * 2 * C + ch]     = s;
    partial[(size_t)blockIdx.x * 2 * C + C + ch] = sq;
}

__global__ void bn_finalize(const float* __restrict__ partial, int nb, int C, float fN,
                            const float* __restrict__ g, const float* __restrict__ be,
                            float* __restrict__ scale, float* __restrict__ shift) {
    int ch = threadIdx.x;
    if (ch >= C) return;
    float s = 0.f, sq = 0.f;
    for (int b = 0; b < nb; ++b) {
        s  += partial[(size_t)b * 2 * C + ch];
        sq += partial[(size_t)b * 2 * C + C + ch];
    }
    float mean = s / fN;
    float var  = sq / fN - mean * mean;
    float inv  = rsqrtf(var + 1e-5f);
    float sc   = g[ch] * inv;
    scale[ch] = sc;
    shift[ch] = be[ch] - mean * sc;
}

// xbn[n, c] (bf16, stride CP, zero-padded c>=CIN) = scale*x+shift
template <int CIN, int CP>
__global__ void bn_apply(const float* __restrict__ x, const float* __restrict__ scale,
                         const float* __restrict__ shift, unsigned short* __restrict__ xbn) {
    int idx = blockIdx.x * blockDim.x + threadIdx.x;
    if (idx >= NN * CP) return;
    int n = idx / CP, c = idx % CP;
    float v = 0.f;
    if (c < CIN) v = scale[c] * x[(size_t)n * CIN + c] + shift[c];
    xbn[idx] = f2bf(v);
}

// ---------------- fold a_src/a_dst into W:  Wf[cin, j] ----------------
__global__ void fold_kernel(const float* __restrict__ W, const float* __restrict__ as_,
                            const float* __restrict__ ad_, int C,
                            float* __restrict__ Wf) {
    int cin = blockIdx.x;
    int j = threadIdx.x;             // 64
    int h = j & 31;
    const float* a = (j < 32) ? as_ : ad_;
    const float* wrow = W + (size_t)cin * 32 * C + (size_t)h * C;
    const float* arow = a + (size_t)h * C;
    float s = 0.f;
    for (int c = 0; c < C; ++c) s += wrow[c] * arow[c];
    Wf[cin * 64 + j] = s;
}

// Wt[c][h*CP + k] = W[k][h*COUT + c] / 32  (bf16, zero-padded), c in [0,NP)
__global__ void repack_w(const float* __restrict__ W, int CIN, int CP, int COUT,
                         unsigned short* __restrict__ Wt) {
    int c = blockIdx.x;              // [0, NP)
    for (int kk = threadIdx.x; kk < 32 * CP; kk += blockDim.x) {
        int h = kk / CP, k = kk % CP;
        float v = 0.f;
        if (c < COUT && k < CIN) v = W[(size_t)k * (32 * COUT) + h * COUT + c] * (1.f / 32.f);
        Wt[(size_t)c * (32 * CP) + kk] = f2bf(v);
    }
}

// ---------------- fp32 GEMM with fused BN on A (used for the 64-col score GEMM) ----
__global__ __launch_bounds__(256) void gemm_bn(const float* __restrict__ X,
                                               const float* __restrict__ W,
                                               const float* __restrict__ scale,
                                               const float* __restrict__ shift,
                                               int Cin, int HC, float* __restrict__ OUT) {
    __shared__ float As[8][64];
    __shared__ float Bs[8][64];
    int tid = threadIdx.x;
    int n0 = blockIdx.y * 64;
    int j0 = blockIdx.x * 64;
    int tr = tid >> 4, tc = tid & 15;
    float acc[4][4] = {};
    for (int k0 = 0; k0 < Cin; k0 += 8) {
        int idx = tid;
#pragma unroll
        for (int it = 0; it < 2; ++it, idx += 256) {
            int row = idx >> 3, kk = idx & 7;
            int k = k0 + kk;
            float v = 0.f;
            if (k < Cin) v = scale[k] * X[(size_t)(n0 + row) * Cin + k] + shift[k];
            As[kk][row] = v;
        }
        int idx2 = tid;
#pragma unroll
        for (int it = 0; it < 2; ++it, idx2 += 256) {
            int col = idx2 & 63, kr = idx2 >> 6;
            int k = k0 + kr, j = j0 + col;
            float v = 0.f;
            if (k < Cin && j < HC) v = W[(size_t)k * HC + j];
            Bs[kr][col] = v;
        }
        __syncthreads();
#pragma unroll
        for (int kk = 0; kk < 8; ++kk) {
            float a[4], b[4];
#pragma unroll
            for (int i = 0; i < 4; ++i) a[i] = As[kk][tr * 4 + i];
#pragma unroll
            for (int j = 0; j < 4; ++j) b[j] = Bs[kk][tc * 4 + j];
#pragma unroll
            for (int i = 0; i < 4; ++i)
#pragma unroll
                for (int j = 0; j < 4; ++j) acc[i][j] += a[i] * b[j];
        }
        __syncthreads();
    }
#pragma unroll
    for (int i = 0; i < 4; ++i) {
        int row = n0 + tr * 4 + i;
#pragma unroll
        for (int j = 0; j < 4; ++j) {
            int col = j0 + tc * 4 + j;
            if (col < HC) OUT[(size_t)row * HC + col] = acc[i][j];
        }
    }
}

// ---------------- CSR build ----------------
__global__ void deg_init(int* __restrict__ deg) {
    int n = blockIdx.x * blockDim.x + threadIdx.x;
    if (n < NN) deg[n] = 1;   // self-loop
}
__global__ void count_kernel(const int* __restrict__ dst, int* __restrict__ deg) {
    int e = blockIdx.x * blockDim.x + threadIdx.x;
    if (e < NE) atomicAdd(&deg[dst[e]], 1);
}
__global__ void scan_kernel(const int* __restrict__ deg, int* __restrict__ rowptr, int N) {
    __shared__ int lds[1024];
    int t = threadIdx.x;
    int chunk = (N + 1023) / 1024;
    int lo = t * chunk, hi = min(lo + chunk, N);
    int s = 0;
    for (int i = lo; i < hi; ++i) s += deg[i];
    lds[t] = s;
    __syncthreads();
    for (int off = 1; off < 1024; off <<= 1) {
        int v = (t >= off) ? lds[t - off] : 0;
        __syncthreads();
        lds[t] += v;
        __syncthreads();
    }
    int run = lds[t] - s;  // exclusive
    for (int i = lo; i < hi; ++i) { rowptr[i] = run; run += deg[i]; }
    if (t == 1023) rowptr[N] = lds[1023];
}
__global__ void copy_int(const int* __restrict__ a, int* __restrict__ b, int N) {
    int n = blockIdx.x * blockDim.x + threadIdx.x;
    if (n < N) b[n] = a[n];
}
__global__ void scatter_edges(const int* __restrict__ src, const int* __restrict__ dst,
                              int* __restrict__ cursor, int* __restrict__ colsrc) {
    int e = blockIdx.x * blockDim.x + threadIdx.x;
    if (e < NE) {
        int pos = atomicAdd(&cursor[dst[e]], 1);
        colsrc[pos] = src[e];
    }
}
__global__ void scatter_self(int* __restrict__ cursor, int* __restrict__ colsrc) {
    int n = blockIdx.x * blockDim.x + threadIdx.x;
    if (n < NN) {
        int pos = atomicAdd(&cursor[n], 1);
        colsrc[pos] = n;
    }
}

// ---------------- pass A: softmax-aggregate xbn -> z[n, 32*CP] (bf16) ----------------
template <int CIN, int CP>
__global__ __launch_bounds__(256) void agg_x(const unsigned short* __restrict__ xbn,
                                             const float* __restrict__ S,
                                             const int* __restrict__ rowptr,
                                             const int* __restrict__ colsrc,
                                             int n0, unsigned short* __restrict__ z) {
    constexpr int BS = 256, CH = 32, J = CP / 8;
    __shared__ float x_lds[CH * CP];
    __shared__ float w_lds[CH * 32];
    __shared__ int cs_lds[CH];
    __shared__ float sdst[32], m_lds[32], d_lds[32], r_lds[32];
    __shared__ float red[8][32];

    int n = n0 + blockIdx.x;
    int tid = threadIdx.x;
    int start = rowptr[n], end = rowptr[n + 1];
    if (tid < 32) {
        sdst[tid] = S[(size_t)n * 64 + 32 + tid];
        m_lds[tid] = -INFINITY;
        d_lds[tid] = 0.f;
    }
    const int h = tid & 31, g = tid >> 5;
    const int cbase = g * J;
    float acc[J] = {};
    __syncthreads();

    for (int chunk = start; chunk < end; chunk += CH) {
        int ce = min(CH, end - chunk);
        if (tid < ce) cs_lds[tid] = colsrc[chunk + tid];
        __syncthreads();
        // logits (leaky 0.2)
        for (int idx = tid; idx < ce * 32; idx += BS) {
            int e = idx >> 5, hh = idx & 31;
            float l = S[(size_t)cs_lds[e] * 64 + hh] + sdst[hh];
            l = l > 0.f ? l : 0.2f * l;
            w_lds[idx] = l;
        }
        // stage xbn rows (bf16 -> fp32 LDS)
        for (int idx = tid; idx < ce * (CP / 2); idx += BS) {
            int e = idx / (CP / 2), c2 = idx % (CP / 2);
            unsigned int u =
                reinterpret_cast<const unsigned int*>(xbn)[(size_t)cs_lds[e] * (CP / 2) + c2];
            x_lds[e * CP + 2 * c2]     = __uint_as_float(u << 16);
            x_lds[e * CP + 2 * c2 + 1] = __uint_as_float(u & 0xFFFF0000u);
        }
        __syncthreads();
        // per-head chunk max
        float pm = -INFINITY;
        for (int e = g; e < ce; e += 8) pm = fmaxf(pm, w_lds[e * 32 + h]);
        red[g][h] = pm;
        __syncthreads();
        if (tid < 32) {
            float cm = red[0][tid];
#pragma unroll
            for (int s2 = 1; s2 < 8; ++s2) cm = fmaxf(cm, red[s2][tid]);
            float oldm = m_lds[tid], newm = fmaxf(oldm, cm);
            r_lds[tid] = (oldm == -INFINITY) ? 0.f : __expf(oldm - newm);
            m_lds[tid] = newm;
        }
        __syncthreads();
        // w = exp(l - m), partial denom
        float ps = 0.f;
        for (int idx = tid; idx < ce * 32; idx += BS) {
            int hh = idx & 31;
            float v = __expf(w_lds[idx] - m_lds[hh]);
            w_lds[idx] = v;
            ps += v;
        }
        red[g][h] = ps;
        __syncthreads();
        if (tid < 32) {
            float ss = 0.f;
#pragma unroll
            for (int s2 = 0; s2 < 8; ++s2) ss += red[s2][tid];
            d_lds[tid] = d_lds[tid] * r_lds[tid] + ss;
        }
        // rescale accumulators, accumulate this chunk
        float rr = r_lds[h];
#pragma unroll
        for (int j = 0; j < J; ++j) acc[j] *= rr;
        for (int e = 0; e < ce; ++e) {
            float w = w_lds[e * 32 + h];
#pragma unroll
            for (int j = 0; j < J; ++j) acc[j] += w * x_lds[e * CP + cbase + j];
        }
        __syncthreads();
    }
    // normalize + store z row (bf16x2)
    float dinv = 1.f / d_lds[h];
    unsigned int* zp = reinterpret_cast<unsigned int*>(
        z + (size_t)(n - n0) * (32 * CP) + h * CP + cbase);
#pragma unroll
    for (int j2 = 0; j2 < J / 2; ++j2) {
        unsigned int u = (unsigned int)f2bf(acc[2 * j2] * dinv)
                       | ((unsigned int)f2bf(acc[2 * j2 + 1] * dinv) << 16);
        zp[j2] = u;
    }
}

// ---------------- pass B: K-split MFMA GEMM with register double-buffer ----------------
// pbuf[part][m][c] = z_seg @ Wt_seg^T
// __launch_bounds__(64, 3): cap ~168 VGPRs so one full iteration of loads (14 x dwordx4
// = 56 VGPRs) plus the prefetch buffer stays register-resident. Round-3 post-mortem:
// default bounds gave 52 VGPRs -> compiler serialized every load's L2 latency (130 us,
// MfmaUtil 4.7%, duration invariant to occupancy).
typedef __attribute__((ext_vector_type(8))) short bf16x8;
typedef __attribute__((ext_vector_type(4))) float f32x4;

template <int NT, int KP, int KS>
__global__ __launch_bounds__(64, 3) void gemm_z(const unsigned short* __restrict__ z,
                                                const unsigned short* __restrict__ Wt,
                                                float* __restrict__ pbuf) {
    constexpr int KSEG = KP / KS;      // multiple of 64
    constexpr int NPAD = NT * 16;
    constexpr int NK = KSEG / 64;
    int m0 = blockIdx.x * 16;
    int kbeg = blockIdx.y * KSEG;
    int lane = threadIdx.x;
    int mm = lane & 15, quad = lane >> 4;
    const unsigned short* arow = z + (size_t)(m0 + mm) * KP + quad * 8 + kbeg;
    const unsigned short* brow = Wt + (size_t)mm * KP + quad * 8 + kbeg;

    f32x4 acc[NT];
#pragma unroll
    for (int t = 0; t < NT; ++t) acc[t] = f32x4{0.f, 0.f, 0.f, 0.f};

    bf16x8 a[2][2];
    bf16x8 b[2][NT][2];
    // preload iteration 0
    a[0][0] = *reinterpret_cast<const bf16x8*>(arow);
    a[0][1] = *reinterpret_cast<const bf16x8*>(arow + 32);
#pragma unroll
    for (int t = 0; t < NT; ++t) {
        const unsigned short* bp = brow + (size_t)t * 16 * KP;
        b[0][t][0] = *reinterpret_cast<const bf16x8*>(bp);
        b[0][t][1] = *reinterpret_cast<const bf16x8*>(bp + 32);
    }
    for (int it = 0; it < NK; ++it) {
        int cur = it & 1, nxt = cur ^ 1;
        if (it + 1 < NK) {
            int koff = (it + 1) * 64;
            a[nxt][0] = *reinterpret_cast<const bf16x8*>(arow + koff);
            a[nxt][1] = *reinterpret_cast<const bf16x8*>(arow + koff + 32);
#pragma unroll
            for (int t = 0; t < NT; ++t) {
                const unsigned short* bp = brow + (size_t)t * 16 * KP + koff;
                b[nxt][t][0] = *reinterpret_cast<const bf16x8*>(bp);
                b[nxt][t][1] = *reinterpret_cast<const bf16x8*>(bp + 32);
            }
        }
#pragma unroll
        for (int t = 0; t < NT; ++t) {
            acc[t] = __builtin_amdgcn_mfma_f32_16x16x32_bf16(a[cur][0], b[cur][t][0], acc[t], 0, 0, 0);
            acc[t] = __builtin_amdgcn_mfma_f32_16x16x32_bf16(a[cur][1], b[cur][t][1], acc[t], 0, 0, 0);
        }
    }
    int row0 = quad * 4;
    float* pb = pbuf + (size_t)blockIdx.y * NSLAB * NPAD;
#pragma unroll
    for (int t = 0; t < NT; ++t) {
        int c = t * 16 + mm;
#pragma unroll
        for (int r = 0; r < 4; ++r) {
            pb[(size_t)(m0 + row0 + r) * NPAD + c] = acc[t][r];
        }
    }
}

// reduce partials + bias + leaky 0.01 -> xout
__global__ void reduce_parts(const float* __restrict__ pbuf, int KS, int NPAD, int COUT,
                             const float* __restrict__ bias, int n0,
                             float* __restrict__ xout) {
    int idx = blockIdx.x * blockDim.x + threadIdx.x;
    if (idx >= NSLAB * NPAD) return;
    int m = idx / NPAD, c = idx % NPAD;
    if (c >= COUT) return;
    float s = 0.f;
    for (int p = 0; p < KS; ++p) s += pbuf[(size_t)p * NSLAB * NPAD + idx];
    float v = s + bias[c];
    v = v > 0.f ? v : 0.01f * v;
    xout[(size_t)(n0 + m) * COUT + c] = v;
}

// ---------------- pooling + head ----------------
__global__ void pool_kernel(const float* __restrict__ x4, const int* __restrict__ batch,
                            float* __restrict__ pooled, float* __restrict__ counts) {
    int n = blockIdx.x * blockDim.x + threadIdx.x;
    if (n >= NN) return;
    int b = batch[n];
    atomicAdd(&counts[b], 1.f);
#pragma unroll
    for (int c = 0; c < 5; ++c) atomicAdd(&pooled[b * 5 + c], x4[(size_t)n * 5 + c]);
}

__global__ void head_kernel(const float* __restrict__ pooled, const float* __restrict__ counts,
                            const float* __restrict__ cond, const float* __restrict__ fcW,
                            const float* __restrict__ fcb, float* __restrict__ out) {
    __shared__ float condd[100];
    int g = threadIdx.x;  // 256
    if (g < 100) condd[g] = cond[g];
    __syncthreads();
    float z = fcb[0];
    float cnt = fmaxf(counts[g], 1.f);
#pragma unroll
    for (int c = 0; c < 5; ++c) z += (pooled[g * 5 + c] / cnt) * fcW[c];
    float cz = 0.f;
    for (int j = 0; j < 100; ++j) cz += condd[j] * fcW[5 + j];
    z += cz;
    out[g] = 1.f / (1.f + __expf(-z));
}

// ---------------- per-layer driver ----------------
struct LayerBufs {
    float* partial; float* scale; float* shift; float* Wf;
    unsigned short* xbn; unsigned short* Wt; unsigned short* zbuf;
    float* Sbuf; float* pbuf; const int* rowptr; const int* colsrc;
};

template <int CIN, int CP, int COUT, int NP, int NT, int KS>
static void run_layer(const float* xin, const float* W, const float* As_, const float* Ad_,
                      const float* Bv, const float* G, const float* Be,
                      float* xout, const LayerBufs& B, hipStream_t stream) {
    constexpr int KP = 32 * CP;
    constexpr int NPAD = NT * 16;
    bn_partial<<<256, 128, 0, stream>>>(xin, NN, CIN, B.partial);
    bn_finalize<<<1, 128, 0, stream>>>(B.partial, 256, CIN, (float)NN, G, Be, B.scale, B.shift);
    bn_apply<CIN, CP><<<(NN * CP + 255) / 256, 256, 0, stream>>>(xin, B.scale, B.shift, B.xbn);
    fold_kernel<<<CIN, 64, 0, stream>>>(W, As_, Ad_, COUT, B.Wf);
    gemm_bn<<<dim3(1, NN / 64), 256, 0, stream>>>(xin, B.Wf, B.scale, B.shift, CIN, 64, B.Sbuf);
    repack_w<<<NP, 256, 0, stream>>>(W, CIN, CP, COUT, B.Wt);
    for (int s = 0; s < 2; ++s) {
        int n0 = s * NSLAB;
        agg_x<CIN, CP><<<NSLAB, 256, 0, stream>>>(B.xbn, B.Sbuf, B.rowptr, B.colsrc, n0, B.zbuf);
        gemm_z<NT, KP, KS><<<dim3(NSLAB / 16, KS), 64, 0, stream>>>(B.zbuf, B.Wt, B.pbuf);
        reduce_parts<<<(NSLAB * NPAD + 255) / 256, 256, 0, stream>>>(
            B.pbuf, KS, NPAD, COUT, Bv, n0, xout);
    }
}

extern "C" void kernel_launch(void* const* d_in, const int* in_sizes, int n_in,
                              void* d_out, int out_size, void* d_ws, size_t ws_size,
                              hipStream_t stream) {
    (void)in_sizes; (void)n_in; (void)out_size;
    const float* x     = (const float*)d_in[0];
    const int*   ei    = (const int*)d_in[1];
    const int*   batch = (const int*)d_in[2];
    const float* cond  = (const float*)d_in[3];
    const float* W[4]  = {(const float*)d_in[4],  (const float*)d_in[8],
                          (const float*)d_in[12], (const float*)d_in[16]};
    const float* Asp[4] = {(const float*)d_in[5],  (const float*)d_in[9],
                           (const float*)d_in[13], (const float*)d_in[17]};
    const float* Adp[4] = {(const float*)d_in[6],  (const float*)d_in[10],
                           (const float*)d_in[14], (const float*)d_in[18]};
    const float* Bv[4]  = {(const float*)d_in[7],  (const float*)d_in[11],
                           (const float*)d_in[15], (const float*)d_in[19]};
    const float* G[4]   = {(const float*)d_in[20], (const float*)d_in[22],
                           (const float*)d_in[24], (const float*)d_in[26]};
    const float* Be[4]  = {(const float*)d_in[21], (const float*)d_in[23],
                           (const float*)d_in[25], (const float*)d_in[27]};
    const float* fcW = (const float*)d_in[30];
    const float* fcb = (const float*)d_in[31];
    float* out = (float*)d_out;

    char* base = (char*)d_ws;
    size_t off = 0;
    auto alloc = [&](size_t b) {
        size_t o = off;
        off += (b + 255) & ~(size_t)255;
        return (void*)(base + o);
    };
    unsigned short* zbuf = (unsigned short*)alloc((size_t)NSLAB * 4096 * 2);
    unsigned short* xbn  = (unsigned short*)alloc((size_t)NN * 128 * 2);
    unsigned short* Wt   = (unsigned short*)alloc((size_t)96 * 4096 * 2);
    float* pbuf    = (float*)alloc((size_t)4 * NSLAB * 96 * 4);
    float* xbuf    = (float*)alloc((size_t)NN * 90 * 4);
    float* Sbuf    = (float*)alloc((size_t)NN * 64 * 4);
    float* partial = (float*)alloc((size_t)256 * 2 * 128 * 4);
    float* scale   = (float*)alloc(128 * 4);
    float* shift   = (float*)alloc(128 * 4);
    float* Wf      = (float*)alloc(128 * 64 * 4);
    int* deg     = (int*)alloc((size_t)NN * 4);
    int* rowptr  = (int*)alloc((size_t)(NN + 1) * 4);
    int* cursor  = (int*)alloc((size_t)NN * 4);
    int* colsrc  = (int*)alloc((size_t)(NE + NN) * 4);
    float* pooled = (float*)alloc(256 * 5 * 4);
    float* counts = (float*)alloc(256 * 4);
    if (off > ws_size) return;

    const int* srcp = ei;
    const int* dstp = ei + NE;

    // CSR by dst
    deg_init<<<(NN + 255) / 256, 256, 0, stream>>>(deg);
    count_kernel<<<(NE + 255) / 256, 256, 0, stream>>>(dstp, deg);
    scan_kernel<<<1, 1024, 0, stream>>>(deg, rowptr, NN);
    copy_int<<<(NN + 255) / 256, 256, 0, stream>>>(rowptr, cursor, NN);
    scatter_edges<<<(NE + 255) / 256, 256, 0, stream>>>(srcp, dstp, cursor, colsrc);
    scatter_self<<<(NN + 255) / 256, 256, 0, stream>>>(cursor, colsrc);

    LayerBufs B{partial, scale, shift, Wf, xbn, Wt, zbuf, Sbuf, pbuf, rowptr, colsrc};

    // L1: 128 -> 90 ; L2: 90 -> 45 ; L3: 45 -> 15 ; L4: 15 -> 5
    run_layer<128, 128, 90, 96, 6, 4>(x,    W[0], Asp[0], Adp[0], Bv[0], G[0], Be[0], xbuf, B, stream);
    run_layer< 90,  96, 45, 48, 3, 3>(xbuf, W[1], Asp[1], Adp[1], Bv[1], G[1], Be[1], xbuf, B, stream);
    run_layer< 45,  48, 15, 16, 1, 2>(xbuf, W[2], Asp[2], Adp[2], Bv[2], G[2], Be[2], xbuf, B, stream);
    run_layer< 15,  16,  5, 16, 1, 1>(xbuf, W[3], Asp[3], Adp[3], Bv[3], G[3], Be[3], xbuf, B, stream);

    hipMemsetAsync(pooled, 0, 256 * 5 * 4, stream);
    hipMemsetAsync(counts, 0, 256 * 4, stream);
    pool_kernel<<<(NN + 255) / 256, 256, 0, stream>>>(xbuf, batch, pooled, counts);
    head_kernel<<<1, 256, 0, stream>>>(pooled, counts, cond, fcW, fcb, out);
}

// Round 5
// 1636.659 us; speedup vs baseline: 1.3493x; 1.3493x over previous
//
#include <hip/hip_runtime.h>
#include <hip/hip_bf16.h>

// ---------------- constants ----------------
constexpr int NN = 40000;   // nodes
constexpr int NE = 400000;  // edges (before self-loops)
constexpr int NSLAB = 20000;

__device__ __forceinline__ unsigned short f2bf(float f) {
    unsigned int u = __float_as_uint(f);
    unsigned int r = (u + 0x7FFFu + ((u >> 16) & 1u)) >> 16;
    return (unsigned short)r;
}

// ---------------- BN ----------------
__global__ void bn_partial(const float* __restrict__ x, int N, int C,
                           float* __restrict__ partial) {
    int ch = threadIdx.x;            // blockDim = 128, C <= 128
    if (ch >= C) return;
    float s = 0.f, sq = 0.f;
    for (int n = blockIdx.x; n < N; n += gridDim.x) {
        float v = x[(size_t)n * C + ch];
        s += v; sq += v * v;
    }
    partial[(size_t)blockIdx.x * 2 * C + ch]     = s;
    partial[(size_t)blockIdx.x * 2 * C + C + ch] = sq;
}

__global__ void bn_finalize(const float* __restrict__ partial, int nb, int C, float fN,
                            const float* __restrict__ g, const float* __restrict__ be,
                            float* __restrict__ scale, float* __restrict__ shift) {
    int ch = threadIdx.x;
    if (ch >= C) return;
    float s = 0.f, sq = 0.f;
    for (int b = 0; b < nb; ++b) {
        s  += partial[(size_t)b * 2 * C + ch];
        sq += partial[(size_t)b * 2 * C + C + ch];
    }
    float mean = s / fN;
    float var  = sq / fN - mean * mean;
    float inv  = rsqrtf(var + 1e-5f);
    float sc   = g[ch] * inv;
    scale[ch] = sc;
    shift[ch] = be[ch] - mean * sc;
}

// xbn[n, c] (bf16, stride CP, zero-padded c>=CIN) = scale*x+shift
template <int CIN, int CP>
__global__ void bn_apply(const float* __restrict__ x, const float* __restrict__ scale,
                         const float* __restrict__ shift, unsigned short* __restrict__ xbn) {
    int idx = blockIdx.x * blockDim.x + threadIdx.x;
    if (idx >= NN * CP) return;
    int n = idx / CP, c = idx % CP;
    float v = 0.f;
    if (c < CIN) v = scale[c] * x[(size_t)n * CIN + c] + shift[c];
    xbn[idx] = f2bf(v);
}

// ---------------- fold a_src/a_dst into W:  Wf[cin, j] ----------------
__global__ void fold_kernel(const float* __restrict__ W, const float* __restrict__ as_,
                            const float* __restrict__ ad_, int C,
                            float* __restrict__ Wf) {
    int cin = blockIdx.x;
    int j = threadIdx.x;             // 64
    int h = j & 31;
    const float* a = (j < 32) ? as_ : ad_;
    const float* wrow = W + (size_t)cin * 32 * C + (size_t)h * C;
    const float* arow = a + (size_t)h * C;
    float s = 0.f;
    for (int c = 0; c < C; ++c) s += wrow[c] * arow[c];
    Wf[cin * 64 + j] = s;
}

// Wt[c][h*CP + k] = W[k][h*COUT + c] / 32  (bf16, zero-padded), c in [0,NP)
__global__ void repack_w(const float* __restrict__ W, int CIN, int CP, int COUT,
                         unsigned short* __restrict__ Wt) {
    int c = blockIdx.x;              // [0, NP)
    for (int kk = threadIdx.x; kk < 32 * CP; kk += blockDim.x) {
        int h = kk / CP, k = kk % CP;
        float v = 0.f;
        if (c < COUT && k < CIN) v = W[(size_t)k * (32 * COUT) + h * COUT + c] * (1.f / 32.f);
        Wt[(size_t)c * (32 * CP) + kk] = f2bf(v);
    }
}

// ---------------- fp32 GEMM with fused BN on A (used for the 64-col score GEMM) ----
__global__ __launch_bounds__(256) void gemm_bn(const float* __restrict__ X,
                                               const float* __restrict__ W,
                                               const float* __restrict__ scale,
                                               const float* __restrict__ shift,
                                               int Cin, int HC, float* __restrict__ OUT) {
    __shared__ float As[8][64];
    __shared__ float Bs[8][64];
    int tid = threadIdx.x;
    int n0 = blockIdx.y * 64;
    int j0 = blockIdx.x * 64;
    int tr = tid >> 4, tc = tid & 15;
    float acc[4][4] = {};
    for (int k0 = 0; k0 < Cin; k0 += 8) {
        int idx = tid;
#pragma unroll
        for (int it = 0; it < 2; ++it, idx += 256) {
            int row = idx >> 3, kk = idx & 7;
            int k = k0 + kk;
            float v = 0.f;
            if (k < Cin) v = scale[k] * X[(size_t)(n0 + row) * Cin + k] + shift[k];
            As[kk][row] = v;
        }
        int idx2 = tid;
#pragma unroll
        for (int it = 0; it < 2; ++it, idx2 += 256) {
            int col = idx2 & 63, kr = idx2 >> 6;
            int k = k0 + kr, j = j0 + col;
            float v = 0.f;
            if (k < Cin && j < HC) v = W[(size_t)k * HC + j];
            Bs[kr][col] = v;
        }
        __syncthreads();
#pragma unroll
        for (int kk = 0; kk < 8; ++kk) {
            float a[4], b[4];
#pragma unroll
            for (int i = 0; i < 4; ++i) a[i] = As[kk][tr * 4 + i];
#pragma unroll
            for (int j = 0; j < 4; ++j) b[j] = Bs[kk][tc * 4 + j];
#pragma unroll
            for (int i = 0; i < 4; ++i)
#pragma unroll
                for (int j = 0; j < 4; ++j) acc[i][j] += a[i] * b[j];
        }
        __syncthreads();
    }
#pragma unroll
    for (int i = 0; i < 4; ++i) {
        int row = n0 + tr * 4 + i;
#pragma unroll
        for (int j = 0; j < 4; ++j) {
            int col = j0 + tc * 4 + j;
            if (col < HC) OUT[(size_t)row * HC + col] = acc[i][j];
        }
    }
}

// ---------------- CSR build ----------------
__global__ void deg_init(int* __restrict__ deg) {
    int n = blockIdx.x * blockDim.x + threadIdx.x;
    if (n < NN) deg[n] = 1;   // self-loop
}
__global__ void count_kernel(const int* __restrict__ dst, int* __restrict__ deg) {
    int e = blockIdx.x * blockDim.x + threadIdx.x;
    if (e < NE) atomicAdd(&deg[dst[e]], 1);
}
__global__ void scan_kernel(const int* __restrict__ deg, int* __restrict__ rowptr, int N) {
    __shared__ int lds[1024];
    int t = threadIdx.x;
    int chunk = (N + 1023) / 1024;
    int lo = t * chunk, hi = min(lo + chunk, N);
    int s = 0;
    for (int i = lo; i < hi; ++i) s += deg[i];
    lds[t] = s;
    __syncthreads();
    for (int off = 1; off < 1024; off <<= 1) {
        int v = (t >= off) ? lds[t - off] : 0;
        __syncthreads();
        lds[t] += v;
        __syncthreads();
    }
    int run = lds[t] - s;  // exclusive
    for (int i = lo; i < hi; ++i) { rowptr[i] = run; run += deg[i]; }
    if (t == 1023) rowptr[N] = lds[1023];
}
__global__ void copy_int(const int* __restrict__ a, int* __restrict__ b, int N) {
    int n = blockIdx.x * blockDim.x + threadIdx.x;
    if (n < N) b[n] = a[n];
}
__global__ void scatter_edges(const int* __restrict__ src, const int* __restrict__ dst,
                              int* __restrict__ cursor, int* __restrict__ colsrc) {
    int e = blockIdx.x * blockDim.x + threadIdx.x;
    if (e < NE) {
        int pos = atomicAdd(&cursor[dst[e]], 1);
        colsrc[pos] = src[e];
    }
}
__global__ void scatter_self(int* __restrict__ cursor, int* __restrict__ colsrc) {
    int n = blockIdx.x * blockDim.x + threadIdx.x;
    if (n < NN) {
        int pos = atomicAdd(&cursor[n], 1);
        colsrc[pos] = n;
    }
}

// ---------------- pass A: softmax-aggregate xbn -> z[n, 32*CP] (bf16) ----------------
template <int CIN, int CP>
__global__ __launch_bounds__(256) void agg_x(const unsigned short* __restrict__ xbn,
                                             const float* __restrict__ S,
                                             const int* __restrict__ rowptr,
                                             const int* __restrict__ colsrc,
                                             int n0, unsigned short* __restrict__ z) {
    constexpr int BS = 256, CH = 32, J = CP / 8;
    __shared__ float x_lds[CH * CP];
    __shared__ float w_lds[CH * 32];
    __shared__ int cs_lds[CH];
    __shared__ float sdst[32], m_lds[32], d_lds[32], r_lds[32];
    __shared__ float red[8][32];

    int n = n0 + blockIdx.x;
    int tid = threadIdx.x;
    int start = rowptr[n], end = rowptr[n + 1];
    if (tid < 32) {
        sdst[tid] = S[(size_t)n * 64 + 32 + tid];
        m_lds[tid] = -INFINITY;
        d_lds[tid] = 0.f;
    }
    const int h = tid & 31, g = tid >> 5;
    const int cbase = g * J;
    float acc[J] = {};
    __syncthreads();

    for (int chunk = start; chunk < end; chunk += CH) {
        int ce = min(CH, end - chunk);
        if (tid < ce) cs_lds[tid] = colsrc[chunk + tid];
        __syncthreads();
        // logits (leaky 0.2)
        for (int idx = tid; idx < ce * 32; idx += BS) {
            int e = idx >> 5, hh = idx & 31;
            float l = S[(size_t)cs_lds[e] * 64 + hh] + sdst[hh];
            l = l > 0.f ? l : 0.2f * l;
            w_lds[idx] = l;
        }
        // stage xbn rows (bf16 -> fp32 LDS)
        for (int idx = tid; idx < ce * (CP / 2); idx += BS) {
            int e = idx / (CP / 2), c2 = idx % (CP / 2);
            unsigned int u =
                reinterpret_cast<const unsigned int*>(xbn)[(size_t)cs_lds[e] * (CP / 2) + c2];
            x_lds[e * CP + 2 * c2]     = __uint_as_float(u << 16);
            x_lds[e * CP + 2 * c2 + 1] = __uint_as_float(u & 0xFFFF0000u);
        }
        __syncthreads();
        // per-head chunk max
        float pm = -INFINITY;
        for (int e = g; e < ce; e += 8) pm = fmaxf(pm, w_lds[e * 32 + h]);
        red[g][h] = pm;
        __syncthreads();
        if (tid < 32) {
            float cm = red[0][tid];
#pragma unroll
            for (int s2 = 1; s2 < 8; ++s2) cm = fmaxf(cm, red[s2][tid]);
            float oldm = m_lds[tid], newm = fmaxf(oldm, cm);
            r_lds[tid] = (oldm == -INFINITY) ? 0.f : __expf(oldm - newm);
            m_lds[tid] = newm;
        }
        __syncthreads();
        // w = exp(l - m), partial denom
        float ps = 0.f;
        for (int idx = tid; idx < ce * 32; idx += BS) {
            int hh = idx & 31;
            float v = __expf(w_lds[idx] - m_lds[hh]);
            w_lds[idx] = v;
            ps += v;
        }
        red[g][h] = ps;
        __syncthreads();
        if (tid < 32) {
            float ss = 0.f;
#pragma unroll
            for (int s2 = 0; s2 < 8; ++s2) ss += red[s2][tid];
            d_lds[tid] = d_lds[tid] * r_lds[tid] + ss;
        }
        // rescale accumulators, accumulate this chunk
        float rr = r_lds[h];
#pragma unroll
        for (int j = 0; j < J; ++j) acc[j] *= rr;
        for (int e = 0; e < ce; ++e) {
            float w = w_lds[e * 32 + h];
#pragma unroll
            for (int j = 0; j < J; ++j) acc[j] += w * x_lds[e * CP + cbase + j];
        }
        __syncthreads();
    }
    // normalize + store z row (bf16x2)
    float dinv = 1.f / d_lds[h];
    unsigned int* zp = reinterpret_cast<unsigned int*>(
        z + (size_t)(n - n0) * (32 * CP) + h * CP + cbase);
#pragma unroll
    for (int j2 = 0; j2 < J / 2; ++j2) {
        unsigned int u = (unsigned int)f2bf(acc[2 * j2] * dinv)
                       | ((unsigned int)f2bf(acc[2 * j2 + 1] * dinv) << 16);
        zp[j2] = u;
    }
}

// ---------------- pass B: K-split MFMA GEMM, fully unrolled flat K-loop ----------------
// pbuf[part][m][c] = z_seg @ Wt_seg^T.  One wave = 32 rows (2 M-tiles share B loads).
// Round-4 post-mortem: dynamic-indexed double-buffer arrays went to scratch (VGPR=60,
// VALUBusy 54%). Fix: full unroll, all-static indices, __launch_bounds__(64,3) for a
// ~170-VGPR budget so the compiler hoists loads itself.
typedef __attribute__((ext_vector_type(8))) short bf16x8;
typedef __attribute__((ext_vector_type(4))) float f32x4;

template <int NT, int KP, int KS>
__global__ __launch_bounds__(64, 3) void gemm_z(const unsigned short* __restrict__ z,
                                                const unsigned short* __restrict__ Wt,
                                                float* __restrict__ pbuf) {
    constexpr int KSEG = KP / KS;      // multiple of 64
    constexpr int NPAD = NT * 16;
    constexpr int NK = KSEG / 64;
    int m0 = blockIdx.x * 32;
    int kbeg = blockIdx.y * KSEG;
    int lane = threadIdx.x;
    int mm = lane & 15, quad = lane >> 4;
    const unsigned short* arow0 = z + (size_t)(m0 + mm) * KP + quad * 8 + kbeg;
    const unsigned short* arow1 = arow0 + (size_t)16 * KP;
    const unsigned short* brow = Wt + (size_t)mm * KP + quad * 8 + kbeg;

    f32x4 acc0[NT], acc1[NT];
#pragma unroll
    for (int t = 0; t < NT; ++t) {
        acc0[t] = f32x4{0.f, 0.f, 0.f, 0.f};
        acc1[t] = f32x4{0.f, 0.f, 0.f, 0.f};
    }
#pragma unroll
    for (int it = 0; it < NK; ++it) {
        const int koff = it * 64;
        bf16x8 a00 = *reinterpret_cast<const bf16x8*>(arow0 + koff);
        bf16x8 a01 = *reinterpret_cast<const bf16x8*>(arow0 + koff + 32);
        bf16x8 a10 = *reinterpret_cast<const bf16x8*>(arow1 + koff);
        bf16x8 a11 = *reinterpret_cast<const bf16x8*>(arow1 + koff + 32);
#pragma unroll
        for (int t = 0; t < NT; ++t) {
            const unsigned short* bp = brow + (size_t)t * 16 * KP + koff;
            bf16x8 b0 = *reinterpret_cast<const bf16x8*>(bp);
            bf16x8 b1 = *reinterpret_cast<const bf16x8*>(bp + 32);
            acc0[t] = __builtin_amdgcn_mfma_f32_16x16x32_bf16(a00, b0, acc0[t], 0, 0, 0);
            acc0[t] = __builtin_amdgcn_mfma_f32_16x16x32_bf16(a01, b1, acc0[t], 0, 0, 0);
            acc1[t] = __builtin_amdgcn_mfma_f32_16x16x32_bf16(a10, b0, acc1[t], 0, 0, 0);
            acc1[t] = __builtin_amdgcn_mfma_f32_16x16x32_bf16(a11, b1, acc1[t], 0, 0, 0);
        }
    }
    int row0 = quad * 4;
    float* pb = pbuf + (size_t)blockIdx.y * NSLAB * NPAD;
#pragma unroll
    for (int t = 0; t < NT; ++t) {
        int c = t * 16 + mm;
#pragma unroll
        for (int r = 0; r < 4; ++r) {
            pb[(size_t)(m0 + row0 + r) * NPAD + c]      = acc0[t][r];
            pb[(size_t)(m0 + 16 + row0 + r) * NPAD + c] = acc1[t][r];
        }
    }
}

// reduce partials + bias + leaky 0.01 -> xout
__global__ void reduce_parts(const float* __restrict__ pbuf, int KS, int NPAD, int COUT,
                             const float* __restrict__ bias, int n0,
                             float* __restrict__ xout) {
    int idx = blockIdx.x * blockDim.x + threadIdx.x;
    if (idx >= NSLAB * NPAD) return;
    int m = idx / NPAD, c = idx % NPAD;
    if (c >= COUT) return;
    float s = 0.f;
    for (int p = 0; p < KS; ++p) s += pbuf[(size_t)p * NSLAB * NPAD + idx];
    float v = s + bias[c];
    v = v > 0.f ? v : 0.01f * v;
    xout[(size_t)(n0 + m) * COUT + c] = v;
}

// ---------------- pooling + head ----------------
__global__ void pool_kernel(const float* __restrict__ x4, const int* __restrict__ batch,
                            float* __restrict__ pooled, float* __restrict__ counts) {
    int n = blockIdx.x * blockDim.x + threadIdx.x;
    if (n >= NN) return;
    int b = batch[n];
    atomicAdd(&counts[b], 1.f);
#pragma unroll
    for (int c = 0; c < 5; ++c) atomicAdd(&pooled[b * 5 + c], x4[(size_t)n * 5 + c]);
}

__global__ void head_kernel(const float* __restrict__ pooled, const float* __restrict__ counts,
                            const float* __restrict__ cond, const float* __restrict__ fcW,
                            const float* __restrict__ fcb, float* __restrict__ out) {
    __shared__ float condd[100];
    int g = threadIdx.x;  // 256
    if (g < 100) condd[g] = cond[g];
    __syncthreads();
    float z = fcb[0];
    float cnt = fmaxf(counts[g], 1.f);
#pragma unroll
    for (int c = 0; c < 5; ++c) z += (pooled[g * 5 + c] / cnt) * fcW[c];
    float cz = 0.f;
    for (int j = 0; j < 100; ++j) cz += condd[j] * fcW[5 + j];
    z += cz;
    out[g] = 1.f / (1.f + __expf(-z));
}

// ---------------- per-layer driver ----------------
struct LayerBufs {
    float* partial; float* scale; float* shift; float* Wf;
    unsigned short* xbn; unsigned short* Wt; unsigned short* zbuf;
    float* Sbuf; float* pbuf; const int* rowptr; const int* colsrc;
};

template <int CIN, int CP, int COUT, int NP, int NT, int KS>
static void run_layer(const float* xin, const float* W, const float* As_, const float* Ad_,
                      const float* Bv, const float* G, const float* Be,
                      float* xout, const LayerBufs& B, hipStream_t stream) {
    constexpr int KP = 32 * CP;
    constexpr int NPAD = NT * 16;
    bn_partial<<<256, 128, 0, stream>>>(xin, NN, CIN, B.partial);
    bn_finalize<<<1, 128, 0, stream>>>(B.partial, 256, CIN, (float)NN, G, Be, B.scale, B.shift);
    bn_apply<CIN, CP><<<(NN * CP + 255) / 256, 256, 0, stream>>>(xin, B.scale, B.shift, B.xbn);
    fold_kernel<<<CIN, 64, 0, stream>>>(W, As_, Ad_, COUT, B.Wf);
    gemm_bn<<<dim3(1, NN / 64), 256, 0, stream>>>(xin, B.Wf, B.scale, B.shift, CIN, 64, B.Sbuf);
    repack_w<<<NP, 256, 0, stream>>>(W, CIN, CP, COUT, B.Wt);
    for (int s = 0; s < 2; ++s) {
        int n0 = s * NSLAB;
        agg_x<CIN, CP><<<NSLAB, 256, 0, stream>>>(B.xbn, B.Sbuf, B.rowptr, B.colsrc, n0, B.zbuf);
        gemm_z<NT, KP, KS><<<dim3(NSLAB / 32, KS), 64, 0, stream>>>(B.zbuf, B.Wt, B.pbuf);
        reduce_parts<<<(NSLAB * NPAD + 255) / 256, 256, 0, stream>>>(
            B.pbuf, KS, NPAD, COUT, Bv, n0, xout);
    }
}

extern "C" void kernel_launch(void* const* d_in, const int* in_sizes, int n_in,
                              void* d_out, int out_size, void* d_ws, size_t ws_size,
                              hipStream_t stream) {
    (void)in_sizes; (void)n_in; (void)out_size;
    const float* x     = (const float*)d_in[0];
    const int*   ei    = (const int*)d_in[1];
    const int*   batch = (const int*)d_in[2];
    const float* cond  = (const float*)d_in[3];
    const float* W[4]  = {(const float*)d_in[4],  (const float*)d_in[8],
                          (const float*)d_in[12], (const float*)d_in[16]};
    const float* Asp[4] = {(const float*)d_in[5],  (const float*)d_in[9],
                           (const float*)d_in[13], (const float*)d_in[17]};
    const float* Adp[4] = {(const float*)d_in[6],  (const float*)d_in[10],
                           (const float*)d_in[14], (const float*)d_in[18]};
    const float* Bv[4]  = {(const float*)d_in[7],  (const float*)d_in[11],
                           (const float*)d_in[15], (const float*)d_in[19]};
    const float* G[4]   = {(const float*)d_in[20], (const float*)d_in[22],
                           (const float*)d_in[24], (const float*)d_in[26]};
    const float* Be[4]  = {(const float*)d_in[21], (const float*)d_in[23],
                           (const float*)d_in[25], (const float*)d_in[27]};
    const float* fcW = (const float*)d_in[30];
    const float* fcb = (const float*)d_in[31];
    float* out = (float*)d_out;

    char* base = (char*)d_ws;
    size_t off = 0;
    auto alloc = [&](size_t b) {
        size_t o = off;
        off += (b + 255) & ~(size_t)255;
        return (void*)(base + o);
    };
    unsigned short* zbuf = (unsigned short*)alloc((size_t)NSLAB * 4096 * 2);
    unsigned short* xbn  = (unsigned short*)alloc((size_t)NN * 128 * 2);
    unsigned short* Wt   = (unsigned short*)alloc((size_t)96 * 4096 * 2);
    float* pbuf    = (float*)alloc((size_t)4 * NSLAB * 96 * 4);
    float* xbuf    = (float*)alloc((size_t)NN * 90 * 4);
    float* Sbuf    = (float*)alloc((size_t)NN * 64 * 4);
    float* partial = (float*)alloc((size_t)256 * 2 * 128 * 4);
    float* scale   = (float*)alloc(128 * 4);
    float* shift   = (float*)alloc(128 * 4);
    float* Wf      = (float*)alloc(128 * 64 * 4);
    int* deg     = (int*)alloc((size_t)NN * 4);
    int* rowptr  = (int*)alloc((size_t)(NN + 1) * 4);
    int* cursor  = (int*)alloc((size_t)NN * 4);
    int* colsrc  = (int*)alloc((size_t)(NE + NN) * 4);
    float* pooled = (float*)alloc(256 * 5 * 4);
    float* counts = (float*)alloc(256 * 4);
    if (off > ws_size) return;

    const int* srcp = ei;
    const int* dstp = ei + NE;

    // CSR by dst
    deg_init<<<(NN + 255) / 256, 256, 0, stream>>>(deg);
    count_kernel<<<(NE + 255) / 256, 256, 0, stream>>>(dstp, deg);
    scan_kernel<<<1, 1024, 0, stream>>>(deg, rowptr, NN);
    copy_int<<<(NN + 255) / 256, 256, 0, stream>>>(rowptr, cursor, NN);
    scatter_edges<<<(NE + 255) / 256, 256, 0, stream>>>(srcp, dstp, cursor, colsrc);
    scatter_self<<<(NN + 255) / 256, 256, 0, stream>>>(cursor, colsrc);

    LayerBufs B{partial, scale, shift, Wf, xbn, Wt, zbuf, Sbuf, pbuf, rowptr, colsrc};

    // L1: 128 -> 90 ; L2: 90 -> 45 ; L3: 45 -> 15 ; L4: 15 -> 5
    run_layer<128, 128, 90, 96, 6, 4>(x,    W[0], Asp[0], Adp[0], Bv[0], G[0], Be[0], xbuf, B, stream);
    run_layer< 90,  96, 45, 48, 3, 3>(xbuf, W[1], Asp[1], Adp[1], Bv[1], G[1], Be[1], xbuf, B, stream);
    run_layer< 45,  48, 15, 16, 1, 2>(xbuf, W[2], Asp[2], Adp[2], Bv[2], G[2], Be[2], xbuf, B, stream);
    run_layer< 15,  16,  5, 16, 1, 1>(xbuf, W[3], Asp[3], Adp[3], Bv[3], G[3], Be[3], xbuf, B, stream);

    hipMemsetAsync(pooled, 0, 256 * 5 * 4, stream);
    hipMemsetAsync(counts, 0, 256 * 4, stream);
    pool_kernel<<<(NN + 255) / 256, 256, 0, stream>>>(xbuf, batch, pooled, counts);
    head_kernel<<<1, 256, 0, stream>>>(pooled, counts, cond, fcW, fcb, out);
}

// Round 6
// 1546.153 us; speedup vs baseline: 1.4282x; 1.0585x over previous
//
#include <hip/hip_runtime.h>
#include <hip/hip_bf16.h>

// ---------------- constants ----------------
constexpr int NN = 40000;   // nodes
constexpr int NE = 400000;  // edges (before self-loops)
constexpr int NSLAB = 20000;

__device__ __forceinline__ unsigned short f2bf(float f) {
    unsigned int u = __float_as_uint(f);
    unsigned int r = (u + 0x7FFFu + ((u >> 16) & 1u)) >> 16;
    return (unsigned short)r;
}

// ---------------- BN ----------------
__global__ void bn_partial(const float* __restrict__ x, int N, int C,
                           float* __restrict__ partial) {
    int ch = threadIdx.x;            // blockDim = 128, C <= 128
    if (ch >= C) return;
    float s = 0.f, sq = 0.f;
    for (int n = blockIdx.x; n < N; n += gridDim.x) {
        float v = x[(size_t)n * C + ch];
        s += v; sq += v * v;
    }
    partial[(size_t)blockIdx.x * 2 * C + ch]     = s;
    partial[(size_t)blockIdx.x * 2 * C + C + ch] = sq;
}

__global__ void bn_finalize(const float* __restrict__ partial, int nb, int C, float fN,
                            const float* __restrict__ g, const float* __restrict__ be,
                            float* __restrict__ scale, float* __restrict__ shift) {
    int ch = threadIdx.x;
    if (ch >= C) return;
    float s = 0.f, sq = 0.f;
    for (int b = 0; b < nb; ++b) {
        s  += partial[(size_t)b * 2 * C + ch];
        sq += partial[(size_t)b * 2 * C + C + ch];
    }
    float mean = s / fN;
    float var  = sq / fN - mean * mean;
    float inv  = rsqrtf(var + 1e-5f);
    float sc   = g[ch] * inv;
    scale[ch] = sc;
    shift[ch] = be[ch] - mean * sc;
}

// xbn[n, c] (bf16, stride CP, zero-padded c>=CIN) = scale*x+shift
template <int CIN, int CP>
__global__ void bn_apply(const float* __restrict__ x, const float* __restrict__ scale,
                         const float* __restrict__ shift, unsigned short* __restrict__ xbn) {
    int idx = blockIdx.x * blockDim.x + threadIdx.x;
    if (idx >= NN * CP) return;
    int n = idx / CP, c = idx % CP;
    float v = 0.f;
    if (c < CIN) v = scale[c] * x[(size_t)n * CIN + c] + shift[c];
    xbn[idx] = f2bf(v);
}

// ---------------- fold a_src/a_dst into W:  Wf[cin, j] ----------------
__global__ void fold_kernel(const float* __restrict__ W, const float* __restrict__ as_,
                            const float* __restrict__ ad_, int C,
                            float* __restrict__ Wf) {
    int cin = blockIdx.x;
    int j = threadIdx.x;             // 64
    int h = j & 31;
    const float* a = (j < 32) ? as_ : ad_;
    const float* wrow = W + (size_t)cin * 32 * C + (size_t)h * C;
    const float* arow = a + (size_t)h * C;
    float s = 0.f;
    for (int c = 0; c < C; ++c) s += wrow[c] * arow[c];
    Wf[cin * 64 + j] = s;
}

// Wt[c][h*CP + k] = W[k][h*COUT + c] / 32  (bf16, zero-padded), c in [0,NP)
__global__ void repack_w(const float* __restrict__ W, int CIN, int CP, int COUT,
                         unsigned short* __restrict__ Wt) {
    int c = blockIdx.x;              // [0, NP)
    for (int kk = threadIdx.x; kk < 32 * CP; kk += blockDim.x) {
        int h = kk / CP, k = kk % CP;
        float v = 0.f;
        if (c < COUT && k < CIN) v = W[(size_t)k * (32 * COUT) + h * COUT + c] * (1.f / 32.f);
        Wt[(size_t)c * (32 * CP) + kk] = f2bf(v);
    }
}

// ---------------- fp32 GEMM with fused BN on A (used for the 64-col score GEMM) ----
__global__ __launch_bounds__(256) void gemm_bn(const float* __restrict__ X,
                                               const float* __restrict__ W,
                                               const float* __restrict__ scale,
                                               const float* __restrict__ shift,
                                               int Cin, int HC, float* __restrict__ OUT) {
    __shared__ float As[8][64];
    __shared__ float Bs[8][64];
    int tid = threadIdx.x;
    int n0 = blockIdx.y * 64;
    int j0 = blockIdx.x * 64;
    int tr = tid >> 4, tc = tid & 15;
    float acc[4][4] = {};
    for (int k0 = 0; k0 < Cin; k0 += 8) {
        int idx = tid;
#pragma unroll
        for (int it = 0; it < 2; ++it, idx += 256) {
            int row = idx >> 3, kk = idx & 7;
            int k = k0 + kk;
            float v = 0.f;
            if (k < Cin) v = scale[k] * X[(size_t)(n0 + row) * Cin + k] + shift[k];
            As[kk][row] = v;
        }
        int idx2 = tid;
#pragma unroll
        for (int it = 0; it < 2; ++it, idx2 += 256) {
            int col = idx2 & 63, kr = idx2 >> 6;
            int k = k0 + kr, j = j0 + col;
            float v = 0.f;
            if (k < Cin && j < HC) v = W[(size_t)k * HC + j];
            Bs[kr][col] = v;
        }
        __syncthreads();
#pragma unroll
        for (int kk = 0; kk < 8; ++kk) {
            float a[4], b[4];
#pragma unroll
            for (int i = 0; i < 4; ++i) a[i] = As[kk][tr * 4 + i];
#pragma unroll
            for (int j = 0; j < 4; ++j) b[j] = Bs[kk][tc * 4 + j];
#pragma unroll
            for (int i = 0; i < 4; ++i)
#pragma unroll
                for (int j = 0; j < 4; ++j) acc[i][j] += a[i] * b[j];
        }
        __syncthreads();
    }
#pragma unroll
    for (int i = 0; i < 4; ++i) {
        int row = n0 + tr * 4 + i;
#pragma unroll
        for (int j = 0; j < 4; ++j) {
            int col = j0 + tc * 4 + j;
            if (col < HC) OUT[(size_t)row * HC + col] = acc[i][j];
        }
    }
}

// ---------------- CSR build ----------------
__global__ void deg_init(int* __restrict__ deg) {
    int n = blockIdx.x * blockDim.x + threadIdx.x;
    if (n < NN) deg[n] = 1;   // self-loop
}
__global__ void count_kernel(const int* __restrict__ dst, int* __restrict__ deg) {
    int e = blockIdx.x * blockDim.x + threadIdx.x;
    if (e < NE) atomicAdd(&deg[dst[e]], 1);
}
__global__ void scan_kernel(const int* __restrict__ deg, int* __restrict__ rowptr, int N) {
    __shared__ int lds[1024];
    int t = threadIdx.x;
    int chunk = (N + 1023) / 1024;
    int lo = t * chunk, hi = min(lo + chunk, N);
    int s = 0;
    for (int i = lo; i < hi; ++i) s += deg[i];
    lds[t] = s;
    __syncthreads();
    for (int off = 1; off < 1024; off <<= 1) {
        int v = (t >= off) ? lds[t - off] : 0;
        __syncthreads();
        lds[t] += v;
        __syncthreads();
    }
    int run = lds[t] - s;  // exclusive
    for (int i = lo; i < hi; ++i) { rowptr[i] = run; run += deg[i]; }
    if (t == 1023) rowptr[N] = lds[1023];
}
__global__ void copy_int(const int* __restrict__ a, int* __restrict__ b, int N) {
    int n = blockIdx.x * blockDim.x + threadIdx.x;
    if (n < N) b[n] = a[n];
}
__global__ void scatter_edges(const int* __restrict__ src, const int* __restrict__ dst,
                              int* __restrict__ cursor, int* __restrict__ colsrc) {
    int e = blockIdx.x * blockDim.x + threadIdx.x;
    if (e < NE) {
        int pos = atomicAdd(&cursor[dst[e]], 1);
        colsrc[pos] = src[e];
    }
}
__global__ void scatter_self(int* __restrict__ cursor, int* __restrict__ colsrc) {
    int n = blockIdx.x * blockDim.x + threadIdx.x;
    if (n < NN) {
        int pos = atomicAdd(&cursor[n], 1);
        colsrc[pos] = n;
    }
}

// ---------------- pass A: softmax-aggregate xbn -> z[n, 32*CP] (bf16) ----------------
template <int CIN, int CP>
__global__ __launch_bounds__(256) void agg_x(const unsigned short* __restrict__ xbn,
                                             const float* __restrict__ S,
                                             const int* __restrict__ rowptr,
                                             const int* __restrict__ colsrc,
                                             int n0, unsigned short* __restrict__ z) {
    constexpr int BS = 256, CH = 32, J = CP / 8;
    __shared__ float x_lds[CH * CP];
    __shared__ float w_lds[CH * 32];
    __shared__ int cs_lds[CH];
    __shared__ float sdst[32], m_lds[32], d_lds[32], r_lds[32];
    __shared__ float red[8][32];

    int n = n0 + blockIdx.x;
    int tid = threadIdx.x;
    int start = rowptr[n], end = rowptr[n + 1];
    if (tid < 32) {
        sdst[tid] = S[(size_t)n * 64 + 32 + tid];
        m_lds[tid] = -INFINITY;
        d_lds[tid] = 0.f;
    }
    const int h = tid & 31, g = tid >> 5;
    const int cbase = g * J;
    float acc[J] = {};
    __syncthreads();

    for (int chunk = start; chunk < end; chunk += CH) {
        int ce = min(CH, end - chunk);
        if (tid < ce) cs_lds[tid] = colsrc[chunk + tid];
        __syncthreads();
        // logits (leaky 0.2)
        for (int idx = tid; idx < ce * 32; idx += BS) {
            int e = idx >> 5, hh = idx & 31;
            float l = S[(size_t)cs_lds[e] * 64 + hh] + sdst[hh];
            l = l > 0.f ? l : 0.2f * l;
            w_lds[idx] = l;
        }
        // stage xbn rows (bf16 -> fp32 LDS)
        for (int idx = tid; idx < ce * (CP / 2); idx += BS) {
            int e = idx / (CP / 2), c2 = idx % (CP / 2);
            unsigned int u =
                reinterpret_cast<const unsigned int*>(xbn)[(size_t)cs_lds[e] * (CP / 2) + c2];
            x_lds[e * CP + 2 * c2]     = __uint_as_float(u << 16);
            x_lds[e * CP + 2 * c2 + 1] = __uint_as_float(u & 0xFFFF0000u);
        }
        __syncthreads();
        // per-head chunk max
        float pm = -INFINITY;
        for (int e = g; e < ce; e += 8) pm = fmaxf(pm, w_lds[e * 32 + h]);
        red[g][h] = pm;
        __syncthreads();
        if (tid < 32) {
            float cm = red[0][tid];
#pragma unroll
            for (int s2 = 1; s2 < 8; ++s2) cm = fmaxf(cm, red[s2][tid]);
            float oldm = m_lds[tid], newm = fmaxf(oldm, cm);
            r_lds[tid] = (oldm == -INFINITY) ? 0.f : __expf(oldm - newm);
            m_lds[tid] = newm;
        }
        __syncthreads();
        // w = exp(l - m), partial denom
        float ps = 0.f;
        for (int idx = tid; idx < ce * 32; idx += BS) {
            int hh = idx & 31;
            float v = __expf(w_lds[idx] - m_lds[hh]);
            w_lds[idx] = v;
            ps += v;
        }
        red[g][h] = ps;
        __syncthreads();
        if (tid < 32) {
            float ss = 0.f;
#pragma unroll
            for (int s2 = 0; s2 < 8; ++s2) ss += red[s2][tid];
            d_lds[tid] = d_lds[tid] * r_lds[tid] + ss;
        }
        // rescale accumulators, accumulate this chunk
        float rr = r_lds[h];
#pragma unroll
        for (int j = 0; j < J; ++j) acc[j] *= rr;
        for (int e = 0; e < ce; ++e) {
            float w = w_lds[e * 32 + h];
#pragma unroll
            for (int j = 0; j < J; ++j) acc[j] += w * x_lds[e * CP + cbase + j];
        }
        __syncthreads();
    }
    // normalize + store z row (bf16x2)
    float dinv = 1.f / d_lds[h];
    unsigned int* zp = reinterpret_cast<unsigned int*>(
        z + (size_t)(n - n0) * (32 * CP) + h * CP + cbase);
#pragma unroll
    for (int j2 = 0; j2 < J / 2; ++j2) {
        unsigned int u = (unsigned int)f2bf(acc[2 * j2] * dinv)
                       | ((unsigned int)f2bf(acc[2 * j2 + 1] * dinv) << 16);
        zp[j2] = u;
    }
}

// ---------------- pass B: K-split MFMA GEMM, fully unrolled flat K-loop ----------------
// pbuf[part][m][c] = z_seg @ Wt_seg^T.  One wave = 32 rows (2 M-tiles share B loads).
// Round-4 post-mortem: dynamic-indexed double-buffer arrays went to scratch (VGPR=60,
// VALUBusy 54%). Fix: full unroll, all-static indices, __launch_bounds__(64,3) for a
// ~170-VGPR budget so the compiler hoists loads itself.
typedef __attribute__((ext_vector_type(8))) short bf16x8;
typedef __attribute__((ext_vector_type(4))) float f32x4;

template <int NT, int KP, int KS>
__global__ __launch_bounds__(64, 3) void gemm_z(const unsigned short* __restrict__ z,
                                                const unsigned short* __restrict__ Wt,
                                                float* __restrict__ pbuf) {
    constexpr int KSEG = KP / KS;      // multiple of 64
    constexpr int NPAD = NT * 16;
    constexpr int NK = KSEG / 64;
    int m0 = blockIdx.x * 32;
    int kbeg = blockIdx.y * KSEG;
    int lane = threadIdx.x;
    int mm = lane & 15, quad = lane >> 4;
    const unsigned short* arow0 = z + (size_t)(m0 + mm) * KP + quad * 8 + kbeg;
    const unsigned short* arow1 = arow0 + (size_t)16 * KP;
    const unsigned short* brow = Wt + (size_t)mm * KP + quad * 8 + kbeg;

    f32x4 acc0[NT], acc1[NT];
#pragma unroll
    for (int t = 0; t < NT; ++t) {
        acc0[t] = f32x4{0.f, 0.f, 0.f, 0.f};
        acc1[t] = f32x4{0.f, 0.f, 0.f, 0.f};
    }
#pragma unroll
    for (int it = 0; it < NK; ++it) {
        const int koff = it * 64;
        bf16x8 a00 = *reinterpret_cast<const bf16x8*>(arow0 + koff);
        bf16x8 a01 = *reinterpret_cast<const bf16x8*>(arow0 + koff + 32);
        bf16x8 a10 = *reinterpret_cast<const bf16x8*>(arow1 + koff);
        bf16x8 a11 = *reinterpret_cast<const bf16x8*>(arow1 + koff + 32);
#pragma unroll
        for (int t = 0; t < NT; ++t) {
            const unsigned short* bp = brow + (size_t)t * 16 * KP + koff;
            bf16x8 b0 = *reinterpret_cast<const bf16x8*>(bp);
            bf16x8 b1 = *reinterpret_cast<const bf16x8*>(bp + 32);
            acc0[t] = __builtin_amdgcn_mfma_f32_16x16x32_bf16(a00, b0, acc0[t], 0, 0, 0);
            acc0[t] = __builtin_amdgcn_mfma_f32_16x16x32_bf16(a01, b1, acc0[t], 0, 0, 0);
            acc1[t] = __builtin_amdgcn_mfma_f32_16x16x32_bf16(a10, b0, acc1[t], 0, 0, 0);
            acc1[t] = __builtin_amdgcn_mfma_f32_16x16x32_bf16(a11, b1, acc1[t], 0, 0, 0);
        }
    }
    int row0 = quad * 4;
    float* pb = pbuf + (size_t)blockIdx.y * NSLAB * NPAD;
#pragma unroll
    for (int t = 0; t < NT; ++t) {
        int c = t * 16 + mm;
#pragma unroll
        for (int r = 0; r < 4; ++r) {
            pb[(size_t)(m0 + row0 + r) * NPAD + c]      = acc0[t][r];
            pb[(size_t)(m0 + 16 + row0 + r) * NPAD + c] = acc1[t][r];
        }
    }
}

// reduce partials + bias + leaky 0.01 -> xout
__global__ void reduce_parts(const float* __restrict__ pbuf, int KS, int NPAD, int COUT,
                             const float* __restrict__ bias, int n0,
                             float* __restrict__ xout) {
    int idx = blockIdx.x * blockDim.x + threadIdx.x;
    if (idx >= NSLAB * NPAD) return;
    int m = idx / NPAD, c = idx % NPAD;
    if (c >= COUT) return;
    float s = 0.f;
    for (int p = 0; p < KS; ++p) s += pbuf[(size_t)p * NSLAB * NPAD + idx];
    float v = s + bias[c];
    v = v > 0.f ? v : 0.01f * v;
    xout[(size_t)(n0 + m) * COUT + c] = v;
}

// ---------------- fused mean-pool + FC + sigmoid ----------------
// One block (64 lanes) per graph. batch is sorted -> binary search node range.
// Round-5 post-mortem: pool_kernel's 240K same-address global atomics on a sorted
// batch serialized (99 us at 1% HBM, 0.01% VALU). Zero-atomic rewrite.
__global__ __launch_bounds__(64) void pool_head(const float* __restrict__ x4,
                                                const int* __restrict__ batch,
                                                const float* __restrict__ cond,
                                                const float* __restrict__ fcW,
                                                const float* __restrict__ fcb,
                                                float* __restrict__ out) {
    int g = blockIdx.x;
    int lane = threadIdx.x;
    // lower_bound(batch, g) and lower_bound(batch, g+1)
    int lo = 0, hi = NN;
    while (lo < hi) { int mid = (lo + hi) >> 1; if (batch[mid] < g) lo = mid + 1; else hi = mid; }
    int lo2 = lo, hi2 = NN;
    while (lo2 < hi2) { int mid = (lo2 + hi2) >> 1; if (batch[mid] < g + 1) lo2 = mid + 1; else hi2 = mid; }
    int beg = lo, end = lo2;

    float s[5] = {0.f, 0.f, 0.f, 0.f, 0.f};
    for (int n = beg + lane; n < end; n += 64) {
#pragma unroll
        for (int c = 0; c < 5; ++c) s[c] += x4[(size_t)n * 5 + c];
    }
    // conditional part (same for all graphs; cheap)
    float cz = 0.f;
    if (lane < 100) cz = cond[lane] * fcW[5 + lane];
    if (lane + 64 < 100) cz += cond[lane + 64] * fcW[5 + lane + 64];
    // wave reduction
#pragma unroll
    for (int off = 32; off > 0; off >>= 1) {
#pragma unroll
        for (int c = 0; c < 5; ++c) s[c] += __shfl_down(s[c], off, 64);
        cz += __shfl_down(cz, off, 64);
    }
    if (lane == 0) {
        float cnt = fmaxf((float)(end - beg), 1.f);
        float zv = fcb[0] + cz;
#pragma unroll
        for (int c = 0; c < 5; ++c) zv += (s[c] / cnt) * fcW[c];
        out[g] = 1.f / (1.f + __expf(-zv));
    }
}

// ---------------- per-layer driver ----------------
struct LayerBufs {
    float* partial; float* scale; float* shift; float* Wf;
    unsigned short* xbn; unsigned short* Wt; unsigned short* zbuf;
    float* Sbuf; float* pbuf; const int* rowptr; const int* colsrc;
};

template <int CIN, int CP, int COUT, int NP, int NT, int KS>
static void run_layer(const float* xin, const float* W, const float* As_, const float* Ad_,
                      const float* Bv, const float* G, const float* Be,
                      float* xout, const LayerBufs& B, hipStream_t stream) {
    constexpr int KP = 32 * CP;
    constexpr int NPAD = NT * 16;
    bn_partial<<<256, 128, 0, stream>>>(xin, NN, CIN, B.partial);
    bn_finalize<<<1, 128, 0, stream>>>(B.partial, 256, CIN, (float)NN, G, Be, B.scale, B.shift);
    bn_apply<CIN, CP><<<(NN * CP + 255) / 256, 256, 0, stream>>>(xin, B.scale, B.shift, B.xbn);
    fold_kernel<<<CIN, 64, 0, stream>>>(W, As_, Ad_, COUT, B.Wf);
    gemm_bn<<<dim3(1, NN / 64), 256, 0, stream>>>(xin, B.Wf, B.scale, B.shift, CIN, 64, B.Sbuf);
    repack_w<<<NP, 256, 0, stream>>>(W, CIN, CP, COUT, B.Wt);
    for (int s = 0; s < 2; ++s) {
        int n0 = s * NSLAB;
        agg_x<CIN, CP><<<NSLAB, 256, 0, stream>>>(B.xbn, B.Sbuf, B.rowptr, B.colsrc, n0, B.zbuf);
        gemm_z<NT, KP, KS><<<dim3(NSLAB / 32, KS), 64, 0, stream>>>(B.zbuf, B.Wt, B.pbuf);
        reduce_parts<<<(NSLAB * NPAD + 255) / 256, 256, 0, stream>>>(
            B.pbuf, KS, NPAD, COUT, Bv, n0, xout);
    }
}

extern "C" void kernel_launch(void* const* d_in, const int* in_sizes, int n_in,
                              void* d_out, int out_size, void* d_ws, size_t ws_size,
                              hipStream_t stream) {
    (void)in_sizes; (void)n_in; (void)out_size;
    const float* x     = (const float*)d_in[0];
    const int*   ei    = (const int*)d_in[1];
    const int*   batch = (const int*)d_in[2];
    const float* cond  = (const float*)d_in[3];
    const float* W[4]  = {(const float*)d_in[4],  (const float*)d_in[8],
                          (const float*)d_in[12], (const float*)d_in[16]};
    const float* Asp[4] = {(const float*)d_in[5],  (const float*)d_in[9],
                           (const float*)d_in[13], (const float*)d_in[17]};
    const float* Adp[4] = {(const float*)d_in[6],  (const float*)d_in[10],
                           (const float*)d_in[14], (const float*)d_in[18]};
    const float* Bv[4]  = {(const float*)d_in[7],  (const float*)d_in[11],
                           (const float*)d_in[15], (const float*)d_in[19]};
    const float* G[4]   = {(const float*)d_in[20], (const float*)d_in[22],
                           (const float*)d_in[24], (const float*)d_in[26]};
    const float* Be[4]  = {(const float*)d_in[21], (const float*)d_in[23],
                           (const float*)d_in[25], (const float*)d_in[27]};
    const float* fcW = (const float*)d_in[30];
    const float* fcb = (const float*)d_in[31];
    float* out = (float*)d_out;

    char* base = (char*)d_ws;
    size_t off = 0;
    auto alloc = [&](size_t b) {
        size_t o = off;
        off += (b + 255) & ~(size_t)255;
        return (void*)(base + o);
    };
    unsigned short* zbuf = (unsigned short*)alloc((size_t)NSLAB * 4096 * 2);
    unsigned short* xbn  = (unsigned short*)alloc((size_t)NN * 128 * 2);
    unsigned short* Wt   = (unsigned short*)alloc((size_t)96 * 4096 * 2);
    float* pbuf    = (float*)alloc((size_t)4 * NSLAB * 96 * 4);
    float* xbuf    = (float*)alloc((size_t)NN * 90 * 4);
    float* Sbuf    = (float*)alloc((size_t)NN * 64 * 4);
    float* partial = (float*)alloc((size_t)256 * 2 * 128 * 4);
    float* scale   = (float*)alloc(128 * 4);
    float* shift   = (float*)alloc(128 * 4);
    float* Wf      = (float*)alloc(128 * 64 * 4);
    int* deg     = (int*)alloc((size_t)NN * 4);
    int* rowptr  = (int*)alloc((size_t)(NN + 1) * 4);
    int* cursor  = (int*)alloc((size_t)NN * 4);
    int* colsrc  = (int*)alloc((size_t)(NE + NN) * 4);
    if (off > ws_size) return;

    const int* srcp = ei;
    const int* dstp = ei + NE;

    // CSR by dst
    deg_init<<<(NN + 255) / 256, 256, 0, stream>>>(deg);
    count_kernel<<<(NE + 255) / 256, 256, 0, stream>>>(dstp, deg);
    scan_kernel<<<1, 1024, 0, stream>>>(deg, rowptr, NN);
    copy_int<<<(NN + 255) / 256, 256, 0, stream>>>(rowptr, cursor, NN);
    scatter_edges<<<(NE + 255) / 256, 256, 0, stream>>>(srcp, dstp, cursor, colsrc);
    scatter_self<<<(NN + 255) / 256, 256, 0, stream>>>(cursor, colsrc);

    LayerBufs B{partial, scale, shift, Wf, xbn, Wt, zbuf, Sbuf, pbuf, rowptr, colsrc};

    // L1: 128 -> 90 ; L2: 90 -> 45 ; L3: 45 -> 15 ; L4: 15 -> 5
    run_layer<128, 128, 90, 96, 6, 4>(x,    W[0], Asp[0], Adp[0], Bv[0], G[0], Be[0], xbuf, B, stream);
    run_layer< 90,  96, 45, 48, 3, 3>(xbuf, W[1], Asp[1], Adp[1], Bv[1], G[1], Be[1], xbuf, B, stream);
    run_layer< 45,  48, 15, 16, 1, 2>(xbuf, W[2], Asp[2], Adp[2], Bv[2], G[2], Be[2], xbuf, B, stream);
    run_layer< 15,  16,  5, 16, 1, 1>(xbuf, W[3], Asp[3], Adp[3], Bv[3], G[3], Be[3], xbuf, B, stream);

    pool_head<<<256, 64, 0, stream>>>(xbuf, batch, cond, fcW, fcb, out);
}

// Round 7
// 1459.930 us; speedup vs baseline: 1.5126x; 1.0591x over previous
//
#include <hip/hip_runtime.h>
#include <hip/hip_bf16.h>

// ---------------- constants ----------------
constexpr int NN = 40000;   // nodes
constexpr int NE = 400000;  // edges (before self-loops)
constexpr int NSLAB = 20000;
constexpr int MPAD = 20096; // 157 * 128 (M-tile overrun padding for pbuf)

__device__ __forceinline__ unsigned short f2bf(float f) {
    unsigned int u = __float_as_uint(f);
    unsigned int r = (u + 0x7FFFu + ((u >> 16) & 1u)) >> 16;
    return (unsigned short)r;
}

// async global->LDS 16B: no VGPR round-trip, loads issue back-to-back.
__device__ __forceinline__ void load_lds16(const unsigned short* g, unsigned short* l) {
    __builtin_amdgcn_global_load_lds(
        (const __attribute__((address_space(1))) unsigned int*)(g),
        (__attribute__((address_space(3))) unsigned int*)(l), 16, 0, 0);
}

// ---------------- BN ----------------
__global__ void bn_partial(const float* __restrict__ x, int N, int C,
                           float* __restrict__ partial) {
    int ch = threadIdx.x;            // blockDim = 128, C <= 128
    if (ch >= C) return;
    float s = 0.f, sq = 0.f;
    for (int n = blockIdx.x; n < N; n += gridDim.x) {
        float v = x[(size_t)n * C + ch];
        s += v; sq += v * v;
    }
    partial[(size_t)blockIdx.x * 2 * C + ch]     = s;
    partial[(size_t)blockIdx.x * 2 * C + C + ch] = sq;
}

__global__ void bn_finalize(const float* __restrict__ partial, int nb, int C, float fN,
                            const float* __restrict__ g, const float* __restrict__ be,
                            float* __restrict__ scale, float* __restrict__ shift) {
    int ch = threadIdx.x;
    if (ch >= C) return;
    float s = 0.f, sq = 0.f;
    for (int b = 0; b < nb; ++b) {
        s  += partial[(size_t)b * 2 * C + ch];
        sq += partial[(size_t)b * 2 * C + C + ch];
    }
    float mean = s / fN;
    float var  = sq / fN - mean * mean;
    float inv  = rsqrtf(var + 1e-5f);
    float sc   = g[ch] * inv;
    scale[ch] = sc;
    shift[ch] = be[ch] - mean * sc;
}

// xbn[n, c] (bf16, stride CP, zero-padded c>=CIN) = scale*x+shift
template <int CIN, int CP>
__global__ void bn_apply(const float* __restrict__ x, const float* __restrict__ scale,
                         const float* __restrict__ shift, unsigned short* __restrict__ xbn) {
    int idx = blockIdx.x * blockDim.x + threadIdx.x;
    if (idx >= NN * CP) return;
    int n = idx / CP, c = idx % CP;
    float v = 0.f;
    if (c < CIN) v = scale[c] * x[(size_t)n * CIN + c] + shift[c];
    xbn[idx] = f2bf(v);
}

// ---------------- fold a_src/a_dst into W:  Wf[cin, j] ----------------
__global__ void fold_kernel(const float* __restrict__ W, const float* __restrict__ as_,
                            const float* __restrict__ ad_, int C,
                            float* __restrict__ Wf) {
    int cin = blockIdx.x;
    int j = threadIdx.x;             // 64
    int h = j & 31;
    const float* a = (j < 32) ? as_ : ad_;
    const float* wrow = W + (size_t)cin * 32 * C + (size_t)h * C;
    const float* arow = a + (size_t)h * C;
    float s = 0.f;
    for (int c = 0; c < C; ++c) s += wrow[c] * arow[c];
    Wf[cin * 64 + j] = s;
}

// Wt[c][h*CP + k] = W[k][h*COUT + c] / 32  (bf16, zero-padded), c in [0,NP)
__global__ void repack_w(const float* __restrict__ W, int CIN, int CP, int COUT,
                         unsigned short* __restrict__ Wt) {
    int c = blockIdx.x;              // [0, NP)
    for (int kk = threadIdx.x; kk < 32 * CP; kk += blockDim.x) {
        int h = kk / CP, k = kk % CP;
        float v = 0.f;
        if (c < COUT && k < CIN) v = W[(size_t)k * (32 * COUT) + h * COUT + c] * (1.f / 32.f);
        Wt[(size_t)c * (32 * CP) + kk] = f2bf(v);
    }
}

// ---------------- fp32 GEMM with fused BN on A (used for the 64-col score GEMM) ----
__global__ __launch_bounds__(256) void gemm_bn(const float* __restrict__ X,
                                               const float* __restrict__ W,
                                               const float* __restrict__ scale,
                                               const float* __restrict__ shift,
                                               int Cin, int HC, float* __restrict__ OUT) {
    __shared__ float As[8][64];
    __shared__ float Bs[8][64];
    int tid = threadIdx.x;
    int n0 = blockIdx.y * 64;
    int j0 = blockIdx.x * 64;
    int tr = tid >> 4, tc = tid & 15;
    float acc[4][4] = {};
    for (int k0 = 0; k0 < Cin; k0 += 8) {
        int idx = tid;
#pragma unroll
        for (int it = 0; it < 2; ++it, idx += 256) {
            int row = idx >> 3, kk = idx & 7;
            int k = k0 + kk;
            float v = 0.f;
            if (k < Cin) v = scale[k] * X[(size_t)(n0 + row) * Cin + k] + shift[k];
            As[kk][row] = v;
        }
        int idx2 = tid;
#pragma unroll
        for (int it = 0; it < 2; ++it, idx2 += 256) {
            int col = idx2 & 63, kr = idx2 >> 6;
            int k = k0 + kr, j = j0 + col;
            float v = 0.f;
            if (k < Cin && j < HC) v = W[(size_t)k * HC + j];
            Bs[kr][col] = v;
        }
        __syncthreads();
#pragma unroll
        for (int kk = 0; kk < 8; ++kk) {
            float a[4], b[4];
#pragma unroll
            for (int i = 0; i < 4; ++i) a[i] = As[kk][tr * 4 + i];
#pragma unroll
            for (int j = 0; j < 4; ++j) b[j] = Bs[kk][tc * 4 + j];
#pragma unroll
            for (int i = 0; i < 4; ++i)
#pragma unroll
                for (int j = 0; j < 4; ++j) acc[i][j] += a[i] * b[j];
        }
        __syncthreads();
    }
#pragma unroll
    for (int i = 0; i < 4; ++i) {
        int row = n0 + tr * 4 + i;
#pragma unroll
        for (int j = 0; j < 4; ++j) {
            int col = j0 + tc * 4 + j;
            if (col < HC) OUT[(size_t)row * HC + col] = acc[i][j];
        }
    }
}

// ---------------- CSR build ----------------
__global__ void deg_init(int* __restrict__ deg) {
    int n = blockIdx.x * blockDim.x + threadIdx.x;
    if (n < NN) deg[n] = 1;   // self-loop
}
__global__ void count_kernel(const int* __restrict__ dst, int* __restrict__ deg) {
    int e = blockIdx.x * blockDim.x + threadIdx.x;
    if (e < NE) atomicAdd(&deg[dst[e]], 1);
}
__global__ void scan_kernel(const int* __restrict__ deg, int* __restrict__ rowptr, int N) {
    __shared__ int lds[1024];
    int t = threadIdx.x;
    int chunk = (N + 1023) / 1024;
    int lo = t * chunk, hi = min(lo + chunk, N);
    int s = 0;
    for (int i = lo; i < hi; ++i) s += deg[i];
    lds[t] = s;
    __syncthreads();
    for (int off = 1; off < 1024; off <<= 1) {
        int v = (t >= off) ? lds[t - off] : 0;
        __syncthreads();
        lds[t] += v;
        __syncthreads();
    }
    int run = lds[t] - s;  // exclusive
    for (int i = lo; i < hi; ++i) { rowptr[i] = run; run += deg[i]; }
    if (t == 1023) rowptr[N] = lds[1023];
}
__global__ void copy_int(const int* __restrict__ a, int* __restrict__ b, int N) {
    int n = blockIdx.x * blockDim.x + threadIdx.x;
    if (n < N) b[n] = a[n];
}
__global__ void scatter_edges(const int* __restrict__ src, const int* __restrict__ dst,
                              int* __restrict__ cursor, int* __restrict__ colsrc) {
    int e = blockIdx.x * blockDim.x + threadIdx.x;
    if (e < NE) {
        int pos = atomicAdd(&cursor[dst[e]], 1);
        colsrc[pos] = src[e];
    }
}
__global__ void scatter_self(int* __restrict__ cursor, int* __restrict__ colsrc) {
    int n = blockIdx.x * blockDim.x + threadIdx.x;
    if (n < NN) {
        int pos = atomicAdd(&cursor[n], 1);
        colsrc[pos] = n;
    }
}

// ---------------- pass A: softmax-aggregate xbn -> z[n, 32*CP] (bf16) ----------------
template <int CIN, int CP>
__global__ __launch_bounds__(256) void agg_x(const unsigned short* __restrict__ xbn,
                                             const float* __restrict__ S,
                                             const int* __restrict__ rowptr,
                                             const int* __restrict__ colsrc,
                                             int n0, unsigned short* __restrict__ z) {
    constexpr int BS = 256, CH = 32, J = CP / 8;
    __shared__ float x_lds[CH * CP];
    __shared__ float w_lds[CH * 32];
    __shared__ int cs_lds[CH];
    __shared__ float sdst[32], m_lds[32], d_lds[32], r_lds[32];
    __shared__ float red[8][32];

    int n = n0 + blockIdx.x;
    int tid = threadIdx.x;
    int start = rowptr[n], end = rowptr[n + 1];
    if (tid < 32) {
        sdst[tid] = S[(size_t)n * 64 + 32 + tid];
        m_lds[tid] = -INFINITY;
        d_lds[tid] = 0.f;
    }
    const int h = tid & 31, g = tid >> 5;
    const int cbase = g * J;
    float acc[J] = {};
    __syncthreads();

    for (int chunk = start; chunk < end; chunk += CH) {
        int ce = min(CH, end - chunk);
        if (tid < ce) cs_lds[tid] = colsrc[chunk + tid];
        __syncthreads();
        // logits (leaky 0.2)
        for (int idx = tid; idx < ce * 32; idx += BS) {
            int e = idx >> 5, hh = idx & 31;
            float l = S[(size_t)cs_lds[e] * 64 + hh] + sdst[hh];
            l = l > 0.f ? l : 0.2f * l;
            w_lds[idx] = l;
        }
        // stage xbn rows (bf16 -> fp32 LDS)
        for (int idx = tid; idx < ce * (CP / 2); idx += BS) {
            int e = idx / (CP / 2), c2 = idx % (CP / 2);
            unsigned int u =
                reinterpret_cast<const unsigned int*>(xbn)[(size_t)cs_lds[e] * (CP / 2) + c2];
            x_lds[e * CP + 2 * c2]     = __uint_as_float(u << 16);
            x_lds[e * CP + 2 * c2 + 1] = __uint_as_float(u & 0xFFFF0000u);
        }
        __syncthreads();
        // per-head chunk max
        float pm = -INFINITY;
        for (int e = g; e < ce; e += 8) pm = fmaxf(pm, w_lds[e * 32 + h]);
        red[g][h] = pm;
        __syncthreads();
        if (tid < 32) {
            float cm = red[0][tid];
#pragma unroll
            for (int s2 = 1; s2 < 8; ++s2) cm = fmaxf(cm, red[s2][tid]);
            float oldm = m_lds[tid], newm = fmaxf(oldm, cm);
            r_lds[tid] = (oldm == -INFINITY) ? 0.f : __expf(oldm - newm);
            m_lds[tid] = newm;
        }
        __syncthreads();
        // w = exp(l - m), partial denom
        float ps = 0.f;
        for (int idx = tid; idx < ce * 32; idx += BS) {
            int hh = idx & 31;
            float v = __expf(w_lds[idx] - m_lds[hh]);
            w_lds[idx] = v;
            ps += v;
        }
        red[g][h] = ps;
        __syncthreads();
        if (tid < 32) {
            float ss = 0.f;
#pragma unroll
            for (int s2 = 0; s2 < 8; ++s2) ss += red[s2][tid];
            d_lds[tid] = d_lds[tid] * r_lds[tid] + ss;
        }
        // rescale accumulators, accumulate this chunk
        float rr = r_lds[h];
#pragma unroll
        for (int j = 0; j < J; ++j) acc[j] *= rr;
        for (int e = 0; e < ce; ++e) {
            float w = w_lds[e * 32 + h];
#pragma unroll
            for (int j = 0; j < J; ++j) acc[j] += w * x_lds[e * CP + cbase + j];
        }
        __syncthreads();
    }
    // normalize + store z row (bf16x2)
    float dinv = 1.f / d_lds[h];
    unsigned int* zp = reinterpret_cast<unsigned int*>(
        z + (size_t)(n - n0) * (32 * CP) + h * CP + cbase);
#pragma unroll
    for (int j2 = 0; j2 < J / 2; ++j2) {
        unsigned int u = (unsigned int)f2bf(acc[2 * j2] * dinv)
                       | ((unsigned int)f2bf(acc[2 * j2 + 1] * dinv) << 16);
        zp[j2] = u;
    }
}

// ---------------- pass B: LDS-tiled MFMA GEMM (m97 structure) ----------------
// pbuf[part][m][c] = z_seg @ Wt_seg^T, M-tile 128, BK=64, double-buffered LDS
// staged via async global_load_lds (width 16). Round-6 post-mortem: register-direct
// feeding serialized every L2 load (~310 cyc/load, MfmaUtil 7%); LDS staging decouples
// load issue from MFMA consumption.
typedef __attribute__((ext_vector_type(8))) short bf16x8;
typedef __attribute__((ext_vector_type(4))) float f32x4;

template <int NT, int KP, int KS>
__global__ __launch_bounds__(256) void gemm_z_t(const unsigned short* __restrict__ z,
                                                const unsigned short* __restrict__ Wt,
                                                float* __restrict__ pbuf) {
    constexpr int NP = NT * 16;
    constexpr int KSEG = KP / KS;       // multiple of 64
    constexpr int NC = KSEG / 64;
    constexpr int MT = 128;
    __shared__ unsigned short Abuf[2][MT * 64];
    __shared__ unsigned short Bbuf[2][NP * 64];

    const int m0 = blockIdx.x * MT;
    const int kbeg = blockIdx.y * KSEG;
    const int tid = threadIdx.x;
    const int wv = tid >> 6;
    const int lane = tid & 63;
    const int mm = lane & 15, quad = lane >> 4;

    auto stage = [&](int buf, int kk) {
        // A tile: 128 rows x 64 k = 1024 granules of 16B
#pragma unroll
        for (int it = 0; it < 4; ++it) {
            int gi = it * 256 + tid;
            int row = gi >> 3, gc = gi & 7;
            int srow = m0 + row;
            if (srow > NSLAB - 1) srow = NSLAB - 1;   // tile overrun: safe garbage, discarded
            const unsigned short* src = z + (size_t)srow * KP + kk + gc * 8;
            unsigned short* dst = &Abuf[buf][(size_t)(it * 256 + wv * 64) * 8];
            load_lds16(src, dst);
        }
        // B tile: NP rows x 64 k
#pragma unroll
        for (int it = 0; it < (NP * 8 + 255) / 256; ++it) {
            int gi = it * 256 + tid;
            if (gi < NP * 8) {
                int row = gi >> 3, gc = gi & 7;
                const unsigned short* src = Wt + (size_t)row * KP + kk + gc * 8;
                unsigned short* dst = &Bbuf[buf][(size_t)(it * 256 + wv * 64) * 8];
                load_lds16(src, dst);
            }
        }
    };

    f32x4 acc[2][NT];
#pragma unroll
    for (int f = 0; f < 2; ++f)
#pragma unroll
        for (int t = 0; t < NT; ++t) acc[f][t] = f32x4{0.f, 0.f, 0.f, 0.f};

    stage(0, kbeg);
    for (int c = 0; c < NC; ++c) {
        asm volatile("s_waitcnt vmcnt(0)" ::: "memory");
        __syncthreads();
        int cur = c & 1;
        if (c + 1 < NC) stage(cur ^ 1, kbeg + (c + 1) * 64);
        const unsigned short* Ab = Abuf[cur];
        const unsigned short* Bb = Bbuf[cur];
#pragma unroll
        for (int h = 0; h < 2; ++h) {
            bf16x8 a0 = *reinterpret_cast<const bf16x8*>(&Ab[(wv * 32 + mm) * 64 + h * 32 + quad * 8]);
            bf16x8 a1 = *reinterpret_cast<const bf16x8*>(&Ab[(wv * 32 + 16 + mm) * 64 + h * 32 + quad * 8]);
#pragma unroll
            for (int t = 0; t < NT; ++t) {
                bf16x8 b = *reinterpret_cast<const bf16x8*>(&Bb[(t * 16 + mm) * 64 + h * 32 + quad * 8]);
                acc[0][t] = __builtin_amdgcn_mfma_f32_16x16x32_bf16(a0, b, acc[0][t], 0, 0, 0);
                acc[1][t] = __builtin_amdgcn_mfma_f32_16x16x32_bf16(a1, b, acc[1][t], 0, 0, 0);
            }
        }
        __syncthreads();
    }

    float* pb = pbuf + (size_t)blockIdx.y * MPAD * NP;
    int row0 = quad * 4;
#pragma unroll
    for (int f = 0; f < 2; ++f) {
#pragma unroll
        for (int t = 0; t < NT; ++t) {
            int cc = t * 16 + mm;
#pragma unroll
            for (int r = 0; r < 4; ++r) {
                int m = m0 + wv * 32 + f * 16 + row0 + r;   // < MPAD by construction
                pb[(size_t)m * NP + cc] = acc[f][t][r];
            }
        }
    }
}

// reduce partials + bias + leaky 0.01 -> xout
__global__ void reduce_parts(const float* __restrict__ pbuf, int KS, int NPAD, int COUT,
                             const float* __restrict__ bias, int n0,
                             float* __restrict__ xout) {
    int idx = blockIdx.x * blockDim.x + threadIdx.x;
    if (idx >= NSLAB * NPAD) return;
    int m = idx / NPAD, c = idx % NPAD;
    if (c >= COUT) return;
    float s = 0.f;
    for (int p = 0; p < KS; ++p) s += pbuf[(size_t)p * MPAD * NPAD + (size_t)m * NPAD + c];
    float v = s + bias[c];
    v = v > 0.f ? v : 0.01f * v;
    xout[(size_t)(n0 + m) * COUT + c] = v;
}

// ---------------- fused mean-pool + FC + sigmoid ----------------
__global__ __launch_bounds__(64) void pool_head(const float* __restrict__ x4,
                                                const int* __restrict__ batch,
                                                const float* __restrict__ cond,
                                                const float* __restrict__ fcW,
                                                const float* __restrict__ fcb,
                                                float* __restrict__ out) {
    int g = blockIdx.x;
    int lane = threadIdx.x;
    int lo = 0, hi = NN;
    while (lo < hi) { int mid = (lo + hi) >> 1; if (batch[mid] < g) lo = mid + 1; else hi = mid; }
    int lo2 = lo, hi2 = NN;
    while (lo2 < hi2) { int mid = (lo2 + hi2) >> 1; if (batch[mid] < g + 1) lo2 = mid + 1; else hi2 = mid; }
    int beg = lo, end = lo2;

    float s[5] = {0.f, 0.f, 0.f, 0.f, 0.f};
    for (int n = beg + lane; n < end; n += 64) {
#pragma unroll
        for (int c = 0; c < 5; ++c) s[c] += x4[(size_t)n * 5 + c];
    }
    float cz = 0.f;
    if (lane < 100) cz = cond[lane] * fcW[5 + lane];
    if (lane + 64 < 100) cz += cond[lane + 64] * fcW[5 + lane + 64];
#pragma unroll
    for (int off = 32; off > 0; off >>= 1) {
#pragma unroll
        for (int c = 0; c < 5; ++c) s[c] += __shfl_down(s[c], off, 64);
        cz += __shfl_down(cz, off, 64);
    }
    if (lane == 0) {
        float cnt = fmaxf((float)(end - beg), 1.f);
        float zv = fcb[0] + cz;
#pragma unroll
        for (int c = 0; c < 5; ++c) zv += (s[c] / cnt) * fcW[c];
        out[g] = 1.f / (1.f + __expf(-zv));
    }
}

// ---------------- per-layer driver ----------------
struct LayerBufs {
    float* partial; float* scale; float* shift; float* Wf;
    unsigned short* xbn; unsigned short* Wt; unsigned short* zbuf;
    float* Sbuf; float* pbuf; const int* rowptr; const int* colsrc;
};

template <int CIN, int CP, int COUT, int NP, int NT, int KS>
static void run_layer(const float* xin, const float* W, const float* As_, const float* Ad_,
                      const float* Bv, const float* G, const float* Be,
                      float* xout, const LayerBufs& B, hipStream_t stream) {
    constexpr int KP = 32 * CP;
    constexpr int NPAD = NT * 16;
    bn_partial<<<256, 128, 0, stream>>>(xin, NN, CIN, B.partial);
    bn_finalize<<<1, 128, 0, stream>>>(B.partial, 256, CIN, (float)NN, G, Be, B.scale, B.shift);
    bn_apply<CIN, CP><<<(NN * CP + 255) / 256, 256, 0, stream>>>(xin, B.scale, B.shift, B.xbn);
    fold_kernel<<<CIN, 64, 0, stream>>>(W, As_, Ad_, COUT, B.Wf);
    gemm_bn<<<dim3(1, NN / 64), 256, 0, stream>>>(xin, B.Wf, B.scale, B.shift, CIN, 64, B.Sbuf);
    repack_w<<<NP, 256, 0, stream>>>(W, CIN, CP, COUT, B.Wt);
    for (int s = 0; s < 2; ++s) {
        int n0 = s * NSLAB;
        agg_x<CIN, CP><<<NSLAB, 256, 0, stream>>>(B.xbn, B.Sbuf, B.rowptr, B.colsrc, n0, B.zbuf);
        gemm_z_t<NT, KP, KS><<<dim3(MPAD / 128, KS), 256, 0, stream>>>(B.zbuf, B.Wt, B.pbuf);
        reduce_parts<<<(NSLAB * NPAD + 255) / 256, 256, 0, stream>>>(
            B.pbuf, KS, NPAD, COUT, Bv, n0, xout);
    }
}

extern "C" void kernel_launch(void* const* d_in, const int* in_sizes, int n_in,
                              void* d_out, int out_size, void* d_ws, size_t ws_size,
                              hipStream_t stream) {
    (void)in_sizes; (void)n_in; (void)out_size;
    const float* x     = (const float*)d_in[0];
    const int*   ei    = (const int*)d_in[1];
    const int*   batch = (const int*)d_in[2];
    const float* cond  = (const float*)d_in[3];
    const float* W[4]  = {(const float*)d_in[4],  (const float*)d_in[8],
                          (const float*)d_in[12], (const float*)d_in[16]};
    const float* Asp[4] = {(const float*)d_in[5],  (const float*)d_in[9],
                           (const float*)d_in[13], (const float*)d_in[17]};
    const float* Adp[4] = {(const float*)d_in[6],  (const float*)d_in[10],
                           (const float*)d_in[14], (const float*)d_in[18]};
    const float* Bv[4]  = {(const float*)d_in[7],  (const float*)d_in[11],
                           (const float*)d_in[15], (const float*)d_in[19]};
    const float* G[4]   = {(const float*)d_in[20], (const float*)d_in[22],
                           (const float*)d_in[24], (const float*)d_in[26]};
    const float* Be[4]  = {(const float*)d_in[21], (const float*)d_in[23],
                           (const float*)d_in[25], (const float*)d_in[27]};
    const float* fcW = (const float*)d_in[30];
    const float* fcb = (const float*)d_in[31];
    float* out = (float*)d_out;

    char* base = (char*)d_ws;
    size_t off = 0;
    auto alloc = [&](size_t b) {
        size_t o = off;
        off += (b + 255) & ~(size_t)255;
        return (void*)(base + o);
    };
    unsigned short* zbuf = (unsigned short*)alloc((size_t)NSLAB * 4096 * 2);
    unsigned short* xbn  = (unsigned short*)alloc((size_t)NN * 128 * 2);
    unsigned short* Wt   = (unsigned short*)alloc((size_t)96 * 4096 * 2);
    float* pbuf    = (float*)alloc((size_t)4 * MPAD * 96 * 4);
    float* xbuf    = (float*)alloc((size_t)NN * 90 * 4);
    float* Sbuf    = (float*)alloc((size_t)NN * 64 * 4);
    float* partial = (float*)alloc((size_t)256 * 2 * 128 * 4);
    float* scale   = (float*)alloc(128 * 4);
    float* shift   = (float*)alloc(128 * 4);
    float* Wf      = (float*)alloc(128 * 64 * 4);
    int* deg     = (int*)alloc((size_t)NN * 4);
    int* rowptr  = (int*)alloc((size_t)(NN + 1) * 4);
    int* cursor  = (int*)alloc((size_t)NN * 4);
    int* colsrc  = (int*)alloc((size_t)(NE + NN) * 4);
    if (off > ws_size) return;

    const int* srcp = ei;
    const int* dstp = ei + NE;

    // CSR by dst
    deg_init<<<(NN + 255) / 256, 256, 0, stream>>>(deg);
    count_kernel<<<(NE + 255) / 256, 256, 0, stream>>>(dstp, deg);
    scan_kernel<<<1, 1024, 0, stream>>>(deg, rowptr, NN);
    copy_int<<<(NN + 255) / 256, 256, 0, stream>>>(rowptr, cursor, NN);
    scatter_edges<<<(NE + 255) / 256, 256, 0, stream>>>(srcp, dstp, cursor, colsrc);
    scatter_self<<<(NN + 255) / 256, 256, 0, stream>>>(cursor, colsrc);

    LayerBufs B{partial, scale, shift, Wf, xbn, Wt, zbuf, Sbuf, pbuf, rowptr, colsrc};

    // L1: 128 -> 90 ; L2: 90 -> 45 ; L3: 45 -> 15 ; L4: 15 -> 5
    run_layer<128, 128, 90, 96, 6, 4>(x,    W[0], Asp[0], Adp[0], Bv[0], G[0], Be[0], xbuf, B, stream);
    run_layer< 90,  96, 45, 48, 3, 4>(xbuf, W[1], Asp[1], Adp[1], Bv[1], G[1], Be[1], xbuf, B, stream);
    run_layer< 45,  48, 15, 16, 1, 4>(xbuf, W[2], Asp[2], Adp[2], Bv[2], G[2], Be[2], xbuf, B, stream);
    run_layer< 15,  16,  5, 16, 1, 2>(xbuf, W[3], Asp[3], Adp[3], Bv[3], G[3], Be[3], xbuf, B, stream);

    pool_head<<<256, 64, 0, stream>>>(xbuf, batch, cond, fcW, fcb, out);
}